// Round 5
// baseline (4314.359 us; speedup 1.0000x reference)
//
#include <hip/hip_runtime.h>
#include <hip/hip_bf16.h>
#include <math.h>

#define BBATCH 4
#define NHEAD  8
#define TSEQ   2048
#define NDIM   256
#define DDIM   512

typedef float f32x4 __attribute__((ext_vector_type(4)));
typedef short bf16x8 __attribute__((ext_vector_type(8)));

__device__ __forceinline__ unsigned short f2bf(float f) {
  __hip_bfloat16 h = __float2bfloat16(f);
  return *reinterpret_cast<unsigned short*>(&h);
}
__device__ __forceinline__ float bf2f(unsigned short u) {
  __hip_bfloat16 h;
  *reinterpret_cast<unsigned short*>(&h) = u;
  return __bfloat162float(h);
}
__device__ __forceinline__ f32x4 mfma16(bf16x8 a, bf16x8 b, f32x4 c) {
  return __builtin_amdgcn_mfma_f32_16x16x32_bf16(a, b, c, 0, 0, 0);
}

// ---------------- Kernel 1: RoPE(Q) -> QR bf16 --------------------------
__global__ __launch_bounds__(256) void rope_kernel(const float* __restrict__ Q,
                                                   unsigned short* __restrict__ QR) {
  long idx = (long)blockIdx.x * 256 + threadIdx.x;     // pair index
  int pair = (int)(idx & 127);                         // N/2 = 128
  long row = idx >> 7;                                 // b*NH*T row
  int t = (int)(row & (TSEQ - 1));
  float2 q = reinterpret_cast<const float2*>(Q)[idx];
  float freq = exp2f(-(float)pair * 0.125f) * 0.15915494309189535f; // 2^(-p/8)/(2pi)
  float phase = (float)t * freq;
  float ph = (phase - floorf(phase)) * 6.283185307179586f;
  float s, c;
  sincosf(ph, &s, &c);
  float o0 = q.x * c - q.y * s;
  float o1 = q.y * c + q.x * s;
  unsigned int pk = (unsigned int)f2bf(o0) | ((unsigned int)f2bf(o1) << 16);
  reinterpret_cast<unsigned int*>(QR)[idx] = pk;
}

// ---------------- Kernel 2: transpose + cast f32[R][C] -> bf16[C][R] ----
__global__ __launch_bounds__(256) void transpose_cast_kernel(
    const float* __restrict__ in, unsigned short* __restrict__ out, int R, int C) {
  __shared__ float tile[64][65];
  long mat = blockIdx.z;
  const float* src = in + mat * (long)R * C;
  unsigned short* dst = out + mat * (long)R * C;
  int c0 = blockIdx.x * 64, r0 = blockIdx.y * 64;
  int tr = threadIdx.x >> 4;          // 0..15
  int tc = (threadIdx.x & 15) * 4;    // 0..60
#pragma unroll
  for (int p = 0; p < 4; ++p) {
    int r = tr + p * 16;
    float4 v = *reinterpret_cast<const float4*>(&src[(long)(r0 + r) * C + c0 + tc]);
    tile[r][tc + 0] = v.x; tile[r][tc + 1] = v.y;
    tile[r][tc + 2] = v.z; tile[r][tc + 3] = v.w;
  }
  __syncthreads();
#pragma unroll
  for (int p = 0; p < 4; ++p) {
    int c = tr + p * 16;
    ushort4 o;
    o.x = f2bf(tile[tc + 0][c]);
    o.y = f2bf(tile[tc + 1][c]);
    o.z = f2bf(tile[tc + 2][c]);
    o.w = f2bf(tile[tc + 3][c]);
    *reinterpret_cast<ushort4*>(&dst[(long)(c0 + c) * R + r0 + tc]) = o;
  }
}

// ---------------- Kernel 3: Qm/Km = l2norm(x @ W^T), bf16x3-split MFMA --
__global__ __launch_bounds__(512) void qkm_kernel(
    const float* __restrict__ x,    // [8192][512]
    const float* __restrict__ wq,   // [256][512]
    const float* __restrict__ wk,   // [256][512]
    unsigned short* __restrict__ Qm,  // [8192][256] bf16
    float* __restrict__ Km) {         // [8192][256] f32
  const bool isK = (blockIdx.y == 1);
  const float* w = isK ? wk : wq;
  int r0 = blockIdx.x * 64;
  int wave = threadIdx.x >> 6, lane = threadIdx.x & 63;
  int wm = wave >> 2, wn = wave & 3;
  int khi = lane >> 4, l16 = lane & 15;
  __shared__ unsigned short Ahi[64 * 32], Alo[64 * 32];
  __shared__ unsigned short Bhi[256 * 32], Blo[256 * 32];
  __shared__ float red[4][64];
  f32x4 acc[2][4] = {};
  for (int k0 = 0; k0 < 512; k0 += 32) {
    { // stage A (x rows): 64x32, one float4 per thread
      int row = threadIdx.x >> 3;
      int kc = (threadIdx.x & 7) * 4;
      float4 v = *reinterpret_cast<const float4*>(&x[(long)(r0 + row) * 512 + k0 + kc]);
      float vv[4] = {v.x, v.y, v.z, v.w};
      unsigned int hx[2], lx[2];
      unsigned short h0 = f2bf(vv[0]), h1 = f2bf(vv[1]), h2 = f2bf(vv[2]), h3 = f2bf(vv[3]);
      hx[0] = (unsigned)h0 | ((unsigned)h1 << 16);
      hx[1] = (unsigned)h2 | ((unsigned)h3 << 16);
      lx[0] = (unsigned)f2bf(vv[0] - bf2f(h0)) | ((unsigned)f2bf(vv[1] - bf2f(h1)) << 16);
      lx[1] = (unsigned)f2bf(vv[2] - bf2f(h2)) | ((unsigned)f2bf(vv[3] - bf2f(h3)) << 16);
      int byt = row * 64 + ((kc * 2) ^ ((row & 3) << 4));
      *reinterpret_cast<uint2*>((char*)Ahi + byt) = make_uint2(hx[0], hx[1]);
      *reinterpret_cast<uint2*>((char*)Alo + byt) = make_uint2(lx[0], lx[1]);
    }
#pragma unroll
    for (int p = 0; p < 4; ++p) { // stage B (w rows): 256x32
      int idx2 = threadIdx.x + p * 512;
      int row = idx2 >> 3;
      int kc = (idx2 & 7) * 4;
      float4 v = *reinterpret_cast<const float4*>(&w[(long)row * 512 + k0 + kc]);
      float vv[4] = {v.x, v.y, v.z, v.w};
      unsigned short h0 = f2bf(vv[0]), h1 = f2bf(vv[1]), h2 = f2bf(vv[2]), h3 = f2bf(vv[3]);
      unsigned int hx0 = (unsigned)h0 | ((unsigned)h1 << 16);
      unsigned int hx1 = (unsigned)h2 | ((unsigned)h3 << 16);
      unsigned int lx0 = (unsigned)f2bf(vv[0] - bf2f(h0)) | ((unsigned)f2bf(vv[1] - bf2f(h1)) << 16);
      unsigned int lx1 = (unsigned)f2bf(vv[2] - bf2f(h2)) | ((unsigned)f2bf(vv[3] - bf2f(h3)) << 16);
      int byt = row * 64 + ((kc * 2) ^ ((row & 3) << 4));
      *reinterpret_cast<uint2*>((char*)Bhi + byt) = make_uint2(hx0, hx1);
      *reinterpret_cast<uint2*>((char*)Blo + byt) = make_uint2(lx0, lx1);
    }
    __syncthreads();
    bf16x8 ah[2], al[2], bh[4], bl[4];
#pragma unroll
    for (int mi = 0; mi < 2; ++mi) {
      int row = wm * 32 + mi * 16 + l16;
      int byt = row * 64 + ((khi * 16) ^ ((row & 3) << 4));
      ah[mi] = *reinterpret_cast<const bf16x8*>((const char*)Ahi + byt);
      al[mi] = *reinterpret_cast<const bf16x8*>((const char*)Alo + byt);
    }
#pragma unroll
    for (int ni = 0; ni < 4; ++ni) {
      int row = wn * 64 + ni * 16 + l16;
      int byt = row * 64 + ((khi * 16) ^ ((row & 3) << 4));
      bh[ni] = *reinterpret_cast<const bf16x8*>((const char*)Bhi + byt);
      bl[ni] = *reinterpret_cast<const bf16x8*>((const char*)Blo + byt);
    }
#pragma unroll
    for (int mi = 0; mi < 2; ++mi)
#pragma unroll
      for (int ni = 0; ni < 4; ++ni) {
        acc[mi][ni] = mfma16(ah[mi], bh[ni], acc[mi][ni]);
        acc[mi][ni] = mfma16(ah[mi], bl[ni], acc[mi][ni]);
        acc[mi][ni] = mfma16(al[mi], bh[ni], acc[mi][ni]);
      }
    __syncthreads();
  }
  // l2norm over the 256 output cols
  float part[2][4];
#pragma unroll
  for (int mi = 0; mi < 2; ++mi)
#pragma unroll
    for (int r = 0; r < 4; ++r) {
      float s = 0.f;
#pragma unroll
      for (int ni = 0; ni < 4; ++ni) s += acc[mi][ni][r] * acc[mi][ni][r];
      part[mi][r] = s;
    }
#pragma unroll
  for (int off = 1; off < 16; off <<= 1)
#pragma unroll
    for (int mi = 0; mi < 2; ++mi)
#pragma unroll
      for (int r = 0; r < 4; ++r) part[mi][r] += __shfl_xor(part[mi][r], off);
  if (l16 == 0) {
#pragma unroll
    for (int mi = 0; mi < 2; ++mi)
#pragma unroll
      for (int r = 0; r < 4; ++r)
        red[wn][wm * 32 + mi * 16 + khi * 4 + r] = part[mi][r];
  }
  __syncthreads();
#pragma unroll
  for (int mi = 0; mi < 2; ++mi)
#pragma unroll
    for (int r = 0; r < 4; ++r) {
      int row = wm * 32 + mi * 16 + khi * 4 + r;
      float ss = red[0][row] + red[1][row] + red[2][row] + red[3][row];
      float scale = 1.f / fmaxf(sqrtf(ss), 1e-12f);
#pragma unroll
      for (int ni = 0; ni < 4; ++ni) {
        int col = wn * 64 + ni * 16 + l16;
        float val = acc[mi][ni][r] * scale;
        if (isK) Km[(long)(r0 + row) * 256 + col] = val;
        else     Qm[(long)(r0 + row) * 256 + col] = f2bf(val);
      }
    }
}

// ---------------- Kernel 4: beta = sigmoid(x @ beta_w^T) ----------------
__global__ __launch_bounds__(64) void beta_kernel(const float* __restrict__ x,
                                                  const float* __restrict__ bw,
                                                  float* __restrict__ beta) {
  long row = blockIdx.x;
  int lane = threadIdx.x;
  const float* xr = x + row * 512;
  float xv[8];
#pragma unroll
  for (int j = 0; j < 8; ++j) xv[j] = xr[lane + j * 64];
#pragma unroll
  for (int h = 0; h < 8; ++h) {
    const float* wr = bw + h * 512;
    float p = 0.f;
#pragma unroll
    for (int j = 0; j < 8; ++j) p += xv[j] * wr[lane + j * 64];
#pragma unroll
    for (int off = 32; off > 0; off >>= 1) p += __shfl_down(p, off);
    if (lane == 0) beta[row * 8 + h] = 1.f / (1.f + expf(-p));
  }
}

// ---------------- Kernel 5: delta-rule scan -> M_new (all f32) ----------
// Layout v3 (R3 layout + DPP butterfly + unroll-4 register pipeline):
// 2048 blocks = 32 bh * 64 dchunks (8 d-cols each), 1 wave per block.
// lane bits: nq (n-group, 8x32 rows) on bits {0,1,3}; dc (d-col) on {2,4,5}.
// Reduction over nq = xor1 (quad_perm), xor2 (quad_perm), xor8 (row_ror:8)
// -- all VALU DPP ops (~4 cyc) instead of DS-routed shuffles (~120 cyc).
__global__ __launch_bounds__(64) void scan_kernel(
    const float* __restrict__ Km,   // [B*T][256]
    const float* __restrict__ xn,   // [B][T][512]
    const float* __restrict__ beta, // [B*T][8]
    const float* __restrict__ M0,   // [BH][256][512]
    float* __restrict__ Mout) {
  int blk = blockIdx.x;          // 2048 = 32 bh * 64 dchunks
  int dch = blk & 63, bh = blk >> 6;
  int b = bh >> 3, h = bh & 7;
  int lane = threadIdx.x;
  int nq = (lane & 3) | ((lane >> 1) & 4);        // bits 0,1,3 -> 0..7
  int dc = ((lane >> 2) & 1) | ((lane >> 3) & 6); // bits 2,4,5 -> 0..7
  int d = dch * 8 + dc;
  int nbase = nq * 32;
  float m[32];
  const float* M0p = M0 + (long)bh * 256 * 512;
#pragma unroll
  for (int i = 0; i < 32; ++i) m[i] = M0p[(long)(nbase + i) * 512 + d];
  const float* kb = Km + (long)b * TSEQ * 256 + nbase;
  const float* vb = xn + (long)b * TSEQ * 512 + d;
  const float* bb = beta + (long)b * TSEQ * 8 + h;

  f32x4 kA[8], kB[8], kC[8], kD[8];
  float vA, vB, vC, vD, bA, bB, bC, bD;
#pragma unroll
  for (int j = 0; j < 8; ++j) {
    kA[j] = *reinterpret_cast<const f32x4*>(kb + 0 * 256 + j * 4);
    kB[j] = *reinterpret_cast<const f32x4*>(kb + 1 * 256 + j * 4);
    kC[j] = *reinterpret_cast<const f32x4*>(kb + 2 * 256 + j * 4);
  }
  vA = vb[0 * 512]; vB = vb[1 * 512]; vC = vb[2 * 512];
  bA = bb[0 * 8];   bB = bb[1 * 8];   bC = bb[2 * 8];

#define LOADROW(KK, VV, BT, ROW)                                             \
  {                                                                          \
    long r_ = (long)(ROW);                                                   \
    const float* kp_ = kb + r_ * 256;                                        \
    _Pragma("unroll")                                                        \
    for (int j = 0; j < 8; ++j)                                              \
      KK[j] = *reinterpret_cast<const f32x4*>(kp_ + j * 4);                  \
    VV = vb[r_ * 512];                                                       \
    BT = bb[r_ * 8];                                                         \
  }

#define SCAN_STEP(KK, VV, BT)                                                \
  {                                                                          \
    float p0 = 0.f, p1 = 0.f, p2 = 0.f, p3 = 0.f;                            \
    _Pragma("unroll")                                                        \
    for (int j = 0; j < 8; ++j) {                                            \
      p0 = fmaf(KK[j].x, m[j * 4 + 0], p0);                                  \
      p1 = fmaf(KK[j].y, m[j * 4 + 1], p1);                                  \
      p2 = fmaf(KK[j].z, m[j * 4 + 2], p2);                                  \
      p3 = fmaf(KK[j].w, m[j * 4 + 3], p3);                                  \
    }                                                                        \
    float p = (p0 + p1) + (p2 + p3);                                         \
    p += __int_as_float(__builtin_amdgcn_update_dpp(                         \
        0, __float_as_int(p), 0xB1, 0xf, 0xf, true));  /* xor1 quad_perm */  \
    p += __int_as_float(__builtin_amdgcn_update_dpp(                         \
        0, __float_as_int(p), 0x4E, 0xf, 0xf, true));  /* xor2 quad_perm */  \
    p += __int_as_float(__builtin_amdgcn_update_dpp(                         \
        0, __float_as_int(p), 0x128, 0xf, 0xf, true)); /* xor8 row_ror:8 */  \
    float delta = BT * (VV - p);                                             \
    _Pragma("unroll")                                                        \
    for (int j = 0; j < 8; ++j) {                                            \
      m[j * 4 + 0] = fmaf(KK[j].x, delta, m[j * 4 + 0]);                     \
      m[j * 4 + 1] = fmaf(KK[j].y, delta, m[j * 4 + 1]);                     \
      m[j * 4 + 2] = fmaf(KK[j].z, delta, m[j * 4 + 2]);                     \
      m[j * 4 + 3] = fmaf(KK[j].w, delta, m[j * 4 + 3]);                     \
    }                                                                        \
  }

  for (int t = 0; t < TSEQ; t += 4) {
    LOADROW(kD, vD, bD, t + 3);                       // t+3 <= 2047 always
    SCAN_STEP(kA, vA, bA);
    LOADROW(kA, vA, bA, min(t + 4, TSEQ - 1));
    SCAN_STEP(kB, vB, bB);
    LOADROW(kB, vB, bB, min(t + 5, TSEQ - 1));
    SCAN_STEP(kC, vC, bC);
    LOADROW(kC, vC, bC, min(t + 6, TSEQ - 1));
    SCAN_STEP(kD, vD, bD);
  }
#undef SCAN_STEP
#undef LOADROW

  float* Mo = Mout + (long)bh * 256 * 512;
#pragma unroll
  for (int i = 0; i < 32; ++i) Mo[(long)(nbase + i) * 512 + d] = m[i];
}

// ---------------- Kernel 6: causal attention y_standard -----------------
// per block: (b,h), 128 t-rows, 256 d-cols; loop s-tiles of 64
__global__ __launch_bounds__(512) void attn_kernel(
    const unsigned short* __restrict__ QR,  // [BH][T][256] bf16
    const unsigned short* __restrict__ Vt,  // [BH][512][T] bf16
    float* __restrict__ Y) {                // [BH][T][512] f32
  int bt = blockIdx.x;
  int bh = blockIdx.y;
  int dch = blockIdx.z;
  int t0 = bt * 128, d0 = dch * 256;
  int wave = threadIdx.x >> 6, lane = threadIdx.x & 63;
  int wr = wave >> 2, wc = wave & 3;
  int khi = lane >> 4, l16 = lane & 15;
  __shared__ unsigned short K_lds[64 * 256];  // 32KB, swizzled
  __shared__ unsigned short S_lds[128 * 64];  // 16KB, swizzled
  const unsigned short* QRb = QR + (long)bh * TSEQ * 256;
  const unsigned short* Vtb = Vt + (long)bh * 512 * TSEQ;
  bf16x8 qa[8];
  {
    int trow = t0 + wave * 16 + l16;
    const unsigned short* qp = QRb + (long)trow * 256 + khi * 8;
#pragma unroll
    for (int ks = 0; ks < 8; ++ks) qa[ks] = *reinterpret_cast<const bf16x8*>(qp + ks * 32);
  }
  f32x4 acc[4][4] = {};
  int nst = bt * 2 + 2;
  for (int st = 0; st < nst; ++st) {
    int s0 = st * 64;
#pragma unroll
    for (int p = 0; p < 4; ++p) {   // stage K tile 64x256 bf16
      int row = (threadIdx.x >> 5) + p * 16;
      int nc = (threadIdx.x & 31) * 8;
      bf16x8 v = *reinterpret_cast<const bf16x8*>(QRb + (long)(s0 + row) * 256 + nc);
      *reinterpret_cast<bf16x8*>((char*)K_lds + row * 512 + ((nc * 2) ^ ((row & 7) << 4))) = v;
    }
    __syncthreads();
    // phase 1: S = Q K^T (wave -> 16 rows x 64 cols)
    f32x4 sacc[4] = {};
#pragma unroll
    for (int ks = 0; ks < 8; ++ks) {
#pragma unroll
      for (int fc = 0; fc < 4; ++fc) {
        int srow = fc * 16 + l16;
        bf16x8 kf = *reinterpret_cast<const bf16x8*>(
            (const char*)K_lds + srow * 512 + ((ks * 64 + khi * 16) ^ ((srow & 7) << 4)));
        sacc[fc] = mfma16(qa[ks], kf, sacc[fc]);
      }
    }
    // mask (strict lower) + cast + store to S_lds
#pragma unroll
    for (int fc = 0; fc < 4; ++fc)
#pragma unroll
      for (int r = 0; r < 4; ++r) {
        int srow = wave * 16 + khi * 4 + r;   // local t row
        int scol = fc * 16 + l16;             // local s col
        float v = ((s0 + scol) < (t0 + srow)) ? sacc[fc][r] : 0.f;
        *reinterpret_cast<unsigned short*>(
            (char*)S_lds + srow * 128 + ((scol * 2) ^ ((srow & 7) << 4))) = f2bf(v);
      }
    __syncthreads();
    // phase 2: O += S @ V  (wave tile 64x64)
#pragma unroll
    for (int k2 = 0; k2 < 2; ++k2) {
      bf16x8 af[4], bfv[4];
#pragma unroll
      for (int mi = 0; mi < 4; ++mi) {
        int row = wr * 64 + mi * 16 + l16;
        af[mi] = *reinterpret_cast<const bf16x8*>(
            (const char*)S_lds + row * 128 + ((k2 * 64 + khi * 16) ^ ((row & 7) << 4)));
      }
#pragma unroll
      for (int ni = 0; ni < 4; ++ni) {
        int d = d0 + wc * 64 + ni * 16 + l16;
        bfv[ni] = *reinterpret_cast<const bf16x8*>(Vtb + (long)d * TSEQ + s0 + k2 * 32 + khi * 8);
      }
#pragma unroll
      for (int mi = 0; mi < 4; ++mi)
#pragma unroll
        for (int ni = 0; ni < 4; ++ni)
          acc[mi][ni] = mfma16(af[mi], bfv[ni], acc[mi][ni]);
    }
    __syncthreads();
  }
  float* yb = Y + (long)bh * TSEQ * 512;
#pragma unroll
  for (int mi = 0; mi < 4; ++mi)
#pragma unroll
    for (int ni = 0; ni < 4; ++ni)
#pragma unroll
      for (int r = 0; r < 4; ++r) {
        int trow = t0 + wr * 64 + mi * 16 + khi * 4 + r;
        int d = d0 + wc * 64 + ni * 16 + l16;
        yb[(long)trow * 512 + d] = acc[mi][ni][r];
      }
}

// ---------------- Kernel 7: y_memory GEMM + LN + gated combine ----------
__global__ __launch_bounds__(512) void combine_kernel(
    const unsigned short* __restrict__ Qm,   // [B*T][256] bf16
    const unsigned short* __restrict__ M0t,  // [BH][512][256] bf16
    const float* __restrict__ mg,            // [NH]
    float* __restrict__ Y) {                 // [BH][T][512] in-place
  int t0 = blockIdx.x * 64;
  int bh = blockIdx.y;
  int b = bh >> 3, h = bh & 7;
  int wv = threadIdx.x >> 6, lane = threadIdx.x & 63;
  int khi = lane >> 4, l16 = lane & 15;
  __shared__ unsigned short A_lds[64 * 256];
  __shared__ float red_s[8][64], red_q[8][64];
  __shared__ float mu_s[64], inv_s[64];
  {
    const unsigned short* src = Qm + ((long)b * TSEQ + t0) * 256;
#pragma unroll
    for (int p = 0; p < 4; ++p) {
      int row = (threadIdx.x >> 5) + p * 16;
      int nc = (threadIdx.x & 31) * 8;
      bf16x8 v = *reinterpret_cast<const bf16x8*>(src + (long)row * 256 + nc);
      *reinterpret_cast<bf16x8*>((char*)A_lds + row * 512 + ((nc * 2) ^ ((row & 7) << 4))) = v;
    }
  }
  __syncthreads();
  f32x4 acc[4][4] = {};
  const unsigned short* Bp = M0t + (long)bh * 512 * 256;
#pragma unroll
  for (int ks = 0; ks < 8; ++ks) {
    bf16x8 a[4], bfr[4];
#pragma unroll
    for (int mi = 0; mi < 4; ++mi) {
      int row = mi * 16 + l16;
      a[mi] = *reinterpret_cast<const bf16x8*>(
          (const char*)A_lds + row * 512 + ((ks * 64 + khi * 16) ^ ((row & 7) << 4)));
    }
#pragma unroll
    for (int ni = 0; ni < 4; ++ni) {
      int d = wv * 64 + ni * 16 + l16;
      bfr[ni] = *reinterpret_cast<const bf16x8*>(Bp + (long)d * 256 + ks * 32 + khi * 8);
    }
#pragma unroll
    for (int mi = 0; mi < 4; ++mi)
#pragma unroll
      for (int ni = 0; ni < 4; ++ni)
        acc[mi][ni] = mfma16(a[mi], bfr[ni], acc[mi][ni]);
  }
  // LayerNorm stats over D=512 (8 waves x 64 cols)
  float ps[4][4], pq[4][4];
#pragma unroll
  for (int mi = 0; mi < 4; ++mi)
#pragma unroll
    for (int r = 0; r < 4; ++r) {
      float s = 0.f, q = 0.f;
#pragma unroll
      for (int ni = 0; ni < 4; ++ni) {
        float v = acc[mi][ni][r];
        s += v; q += v * v;
      }
      ps[mi][r] = s; pq[mi][r] = q;
    }
#pragma unroll
  for (int off = 1; off < 16; off <<= 1)
#pragma unroll
    for (int mi = 0; mi < 4; ++mi)
#pragma unroll
      for (int r = 0; r < 4; ++r) {
        ps[mi][r] += __shfl_xor(ps[mi][r], off);
        pq[mi][r] += __shfl_xor(pq[mi][r], off);
      }
  if (l16 == 0) {
#pragma unroll
    for (int mi = 0; mi < 4; ++mi)
#pragma unroll
      for (int r = 0; r < 4; ++r) {
        int row = mi * 16 + khi * 4 + r;
        red_s[wv][row] = ps[mi][r];
        red_q[wv][row] = pq[mi][r];
      }
  }
  __syncthreads();
  if (threadIdx.x < 64) {
    float s = 0.f, q = 0.f;
#pragma unroll
    for (int w2 = 0; w2 < 8; ++w2) { s += red_s[w2][threadIdx.x]; q += red_q[w2][threadIdx.x]; }
    float mu = s / 512.f;
    float var = q / 512.f - mu * mu;
    mu_s[threadIdx.x] = mu;
    inv_s[threadIdx.x] = rsqrtf(var + 1e-5f);
  }
  __syncthreads();
  float gate = 1.f / (1.f + expf(-mg[h]));
  float omg = 1.f - gate;
  float* yb = Y + ((long)bh * TSEQ + t0) * 512;
#pragma unroll
  for (int mi = 0; mi < 4; ++mi)
#pragma unroll
    for (int r = 0; r < 4; ++r) {
      int row = mi * 16 + khi * 4 + r;
      float mu = mu_s[row], inv = inv_s[row];
#pragma unroll
      for (int ni = 0; ni < 4; ++ni) {
        int d = wv * 64 + ni * 16 + l16;
        long off = (long)row * 512 + d;
        float ymv = (acc[mi][ni][r] - mu) * inv;
        yb[off] = omg * yb[off] + gate * ymv;
      }
    }
}

// ---------------- host launcher -----------------------------------------
extern "C" void kernel_launch(void* const* d_in, const int* in_sizes, int n_in,
                              void* d_out, int out_size, void* d_ws, size_t ws_size,
                              hipStream_t stream) {
  const float* Q      = (const float*)d_in[0];
  const float* V      = (const float*)d_in[1];
  const float* x_raw  = (const float*)d_in[2];
  const float* x_next = (const float*)d_in[3];
  const float* wq     = (const float*)d_in[4];
  const float* wk     = (const float*)d_in[5];
  const float* bw     = (const float*)d_in[6];
  const float* mg     = (const float*)d_in[7];
  const float* M0     = (const float*)d_in[8];
  float* y = (float*)d_out;
  float* Mout = y + (long)32 * 2048 * 512;   // y is B*NH*T*D = 33,554,432 floats

  char* ws = (char*)d_ws;
  unsigned short* QR  = (unsigned short*)(ws);                 // 33,554,432 B
  unsigned short* Vt  = (unsigned short*)(ws + 33554432);      // 67,108,864 B
  unsigned short* M0t = (unsigned short*)(ws + 100663296);     //  8,388,608 B
  unsigned short* Qm  = (unsigned short*)(ws + 109051904);     //  4,194,304 B
  float*  Km          = (float*)(ws + 113246208);              //  8,388,608 B
  float*  beta        = (float*)(ws + 121634816);              //    262,144 B

  rope_kernel<<<dim3(32768), dim3(256), 0, stream>>>(Q, QR);
  transpose_cast_kernel<<<dim3(8, 32, 32), dim3(256), 0, stream>>>(V, Vt, 2048, 512);
  transpose_cast_kernel<<<dim3(8, 4, 32), dim3(256), 0, stream>>>(M0, M0t, 256, 512);
  qkm_kernel<<<dim3(128, 2), dim3(512), 0, stream>>>(x_raw, wq, wk, Qm, Km);
  beta_kernel<<<dim3(8192), dim3(64), 0, stream>>>(x_raw, bw, beta);
  scan_kernel<<<dim3(2048), dim3(64), 0, stream>>>(Km, x_next, beta, M0, Mout);
  attn_kernel<<<dim3(16, 32, 2), dim3(512), 0, stream>>>(QR, Vt, y);
  combine_kernel<<<dim3(32, 32), dim3(512), 0, stream>>>(Qm, M0t, mg, y);
}

// Round 6
// 1080.584 us; speedup vs baseline: 3.9926x; 3.9926x over previous
//
#include <hip/hip_runtime.h>
#include <hip/hip_bf16.h>
#include <math.h>

#define BBATCH 4
#define NHEAD  8
#define TSEQ   2048
#define NDIM   256
#define DDIM   512

typedef float f32x4 __attribute__((ext_vector_type(4)));
typedef short bf16x8 __attribute__((ext_vector_type(8)));

__device__ __forceinline__ unsigned short f2bf(float f) {
  __hip_bfloat16 h = __float2bfloat16(f);
  return *reinterpret_cast<unsigned short*>(&h);
}
__device__ __forceinline__ float bf2f(unsigned short u) {
  __hip_bfloat16 h;
  *reinterpret_cast<unsigned short*>(&h) = u;
  return __bfloat162float(h);
}
__device__ __forceinline__ f32x4 mfma16(bf16x8 a, bf16x8 b, f32x4 c) {
  return __builtin_amdgcn_mfma_f32_16x16x32_bf16(a, b, c, 0, 0, 0);
}

// Kr swizzle (two-level, spreads both row-low and row-mid bits)
#define KSW(t) (((((t) & 7) ^ (((t) >> 3) & 3))) << 4)

// ---------------- Kernel 1: RoPE(Q) -> QR bf16 --------------------------
__global__ __launch_bounds__(256) void rope_kernel(const float* __restrict__ Q,
                                                   unsigned short* __restrict__ QR) {
  long idx = (long)blockIdx.x * 256 + threadIdx.x;
  int pair = (int)(idx & 127);
  long row = idx >> 7;
  int t = (int)(row & (TSEQ - 1));
  float2 q = reinterpret_cast<const float2*>(Q)[idx];
  float freq = exp2f(-(float)pair * 0.125f) * 0.15915494309189535f;
  float phase = (float)t * freq;
  float ph = (phase - floorf(phase)) * 6.283185307179586f;
  float s, c;
  sincosf(ph, &s, &c);
  float o0 = q.x * c - q.y * s;
  float o1 = q.y * c + q.x * s;
  unsigned int pk = (unsigned int)f2bf(o0) | ((unsigned int)f2bf(o1) << 16);
  reinterpret_cast<unsigned int*>(QR)[idx] = pk;
}

// ---------------- Kernel 2: transpose + cast f32[R][C] -> bf16[C][R] ----
__global__ __launch_bounds__(256) void transpose_cast_kernel(
    const float* __restrict__ in, unsigned short* __restrict__ out, int R, int C) {
  __shared__ float tile[64][65];
  long mat = blockIdx.z;
  const float* src = in + mat * (long)R * C;
  unsigned short* dst = out + mat * (long)R * C;
  int c0 = blockIdx.x * 64, r0 = blockIdx.y * 64;
  int tr = threadIdx.x >> 4;
  int tc = (threadIdx.x & 15) * 4;
#pragma unroll
  for (int p = 0; p < 4; ++p) {
    int r = tr + p * 16;
    float4 v = *reinterpret_cast<const float4*>(&src[(long)(r0 + r) * C + c0 + tc]);
    tile[r][tc + 0] = v.x; tile[r][tc + 1] = v.y;
    tile[r][tc + 2] = v.z; tile[r][tc + 3] = v.w;
  }
  __syncthreads();
#pragma unroll
  for (int p = 0; p < 4; ++p) {
    int c = tr + p * 16;
    ushort4 o;
    o.x = f2bf(tile[tc + 0][c]);
    o.y = f2bf(tile[tc + 1][c]);
    o.z = f2bf(tile[tc + 2][c]);
    o.w = f2bf(tile[tc + 3][c]);
    *reinterpret_cast<ushort4*>(&dst[(long)(c0 + c) * R + r0 + tc]) = o;
  }
}

// ---------------- Kernel 3: Qm/Km = l2norm(x @ W^T), bf16x3-split MFMA --
__global__ __launch_bounds__(512) void qkm_kernel(
    const float* __restrict__ x,
    const float* __restrict__ wq,
    const float* __restrict__ wk,
    unsigned short* __restrict__ Qm,
    float* __restrict__ Km) {
  const bool isK = (blockIdx.y == 1);
  const float* w = isK ? wk : wq;
  int r0 = blockIdx.x * 64;
  int wave = threadIdx.x >> 6, lane = threadIdx.x & 63;
  int wm = wave >> 2, wn = wave & 3;
  int khi = lane >> 4, l16 = lane & 15;
  __shared__ unsigned short Ahi[64 * 32], Alo[64 * 32];
  __shared__ unsigned short Bhi[256 * 32], Blo[256 * 32];
  __shared__ float red[4][64];
  f32x4 acc[2][4] = {};
  for (int k0 = 0; k0 < 512; k0 += 32) {
    {
      int row = threadIdx.x >> 3;
      int kc = (threadIdx.x & 7) * 4;
      float4 v = *reinterpret_cast<const float4*>(&x[(long)(r0 + row) * 512 + k0 + kc]);
      float vv[4] = {v.x, v.y, v.z, v.w};
      unsigned int hx[2], lx[2];
      unsigned short h0 = f2bf(vv[0]), h1 = f2bf(vv[1]), h2 = f2bf(vv[2]), h3 = f2bf(vv[3]);
      hx[0] = (unsigned)h0 | ((unsigned)h1 << 16);
      hx[1] = (unsigned)h2 | ((unsigned)h3 << 16);
      lx[0] = (unsigned)f2bf(vv[0] - bf2f(h0)) | ((unsigned)f2bf(vv[1] - bf2f(h1)) << 16);
      lx[1] = (unsigned)f2bf(vv[2] - bf2f(h2)) | ((unsigned)f2bf(vv[3] - bf2f(h3)) << 16);
      int byt = row * 64 + ((kc * 2) ^ ((row & 3) << 4));
      *reinterpret_cast<uint2*>((char*)Ahi + byt) = make_uint2(hx[0], hx[1]);
      *reinterpret_cast<uint2*>((char*)Alo + byt) = make_uint2(lx[0], lx[1]);
    }
#pragma unroll
    for (int p = 0; p < 4; ++p) {
      int idx2 = threadIdx.x + p * 512;
      int row = idx2 >> 3;
      int kc = (idx2 & 7) * 4;
      float4 v = *reinterpret_cast<const float4*>(&w[(long)row * 512 + k0 + kc]);
      float vv[4] = {v.x, v.y, v.z, v.w};
      unsigned short h0 = f2bf(vv[0]), h1 = f2bf(vv[1]), h2 = f2bf(vv[2]), h3 = f2bf(vv[3]);
      unsigned int hx0 = (unsigned)h0 | ((unsigned)h1 << 16);
      unsigned int hx1 = (unsigned)h2 | ((unsigned)h3 << 16);
      unsigned int lx0 = (unsigned)f2bf(vv[0] - bf2f(h0)) | ((unsigned)f2bf(vv[1] - bf2f(h1)) << 16);
      unsigned int lx1 = (unsigned)f2bf(vv[2] - bf2f(h2)) | ((unsigned)f2bf(vv[3] - bf2f(h3)) << 16);
      int byt = row * 64 + ((kc * 2) ^ ((row & 3) << 4));
      *reinterpret_cast<uint2*>((char*)Bhi + byt) = make_uint2(hx0, hx1);
      *reinterpret_cast<uint2*>((char*)Blo + byt) = make_uint2(lx0, lx1);
    }
    __syncthreads();
    bf16x8 ah[2], al[2], bh[4], bl[4];
#pragma unroll
    for (int mi = 0; mi < 2; ++mi) {
      int row = wm * 32 + mi * 16 + l16;
      int byt = row * 64 + ((khi * 16) ^ ((row & 3) << 4));
      ah[mi] = *reinterpret_cast<const bf16x8*>((const char*)Ahi + byt);
      al[mi] = *reinterpret_cast<const bf16x8*>((const char*)Alo + byt);
    }
#pragma unroll
    for (int ni = 0; ni < 4; ++ni) {
      int row = wn * 64 + ni * 16 + l16;
      int byt = row * 64 + ((khi * 16) ^ ((row & 3) << 4));
      bh[ni] = *reinterpret_cast<const bf16x8*>((const char*)Bhi + byt);
      bl[ni] = *reinterpret_cast<const bf16x8*>((const char*)Blo + byt);
    }
#pragma unroll
    for (int mi = 0; mi < 2; ++mi)
#pragma unroll
      for (int ni = 0; ni < 4; ++ni) {
        acc[mi][ni] = mfma16(ah[mi], bh[ni], acc[mi][ni]);
        acc[mi][ni] = mfma16(ah[mi], bl[ni], acc[mi][ni]);
        acc[mi][ni] = mfma16(al[mi], bh[ni], acc[mi][ni]);
      }
    __syncthreads();
  }
  float part[2][4];
#pragma unroll
  for (int mi = 0; mi < 2; ++mi)
#pragma unroll
    for (int r = 0; r < 4; ++r) {
      float s = 0.f;
#pragma unroll
      for (int ni = 0; ni < 4; ++ni) s += acc[mi][ni][r] * acc[mi][ni][r];
      part[mi][r] = s;
    }
#pragma unroll
  for (int off = 1; off < 16; off <<= 1)
#pragma unroll
    for (int mi = 0; mi < 2; ++mi)
#pragma unroll
      for (int r = 0; r < 4; ++r) part[mi][r] += __shfl_xor(part[mi][r], off);
  if (l16 == 0) {
#pragma unroll
    for (int mi = 0; mi < 2; ++mi)
#pragma unroll
      for (int r = 0; r < 4; ++r)
        red[wn][wm * 32 + mi * 16 + khi * 4 + r] = part[mi][r];
  }
  __syncthreads();
#pragma unroll
  for (int mi = 0; mi < 2; ++mi)
#pragma unroll
    for (int r = 0; r < 4; ++r) {
      int row = wm * 32 + mi * 16 + khi * 4 + r;
      float ss = red[0][row] + red[1][row] + red[2][row] + red[3][row];
      float scale = 1.f / fmaxf(sqrtf(ss), 1e-12f);
#pragma unroll
      for (int ni = 0; ni < 4; ++ni) {
        int col = wn * 64 + ni * 16 + l16;
        float val = acc[mi][ni][r] * scale;
        if (isK) Km[(long)(r0 + row) * 256 + col] = val;
        else     Qm[(long)(r0 + row) * 256 + col] = f2bf(val);
      }
    }
}

// ---------------- Kernel 4: beta = sigmoid(x @ beta_w^T) ----------------
__global__ __launch_bounds__(64) void beta_kernel(const float* __restrict__ x,
                                                  const float* __restrict__ bw,
                                                  float* __restrict__ beta) {
  long row = blockIdx.x;
  int lane = threadIdx.x;
  const float* xr = x + row * 512;
  float xv[8];
#pragma unroll
  for (int j = 0; j < 8; ++j) xv[j] = xr[lane + j * 64];
#pragma unroll
  for (int hh = 0; hh < 8; ++hh) {
    const float* wr = bw + hh * 512;
    float p = 0.f;
#pragma unroll
    for (int j = 0; j < 8; ++j) p += xv[j] * wr[lane + j * 64];
#pragma unroll
    for (int off = 32; off > 0; off >>= 1) p += __shfl_down(p, off);
    if (lane == 0) beta[row * 8 + hh] = 1.f / (1.f + expf(-p));
  }
}

// ---------------- Kernel 5a: per-chunk W = (I + diag(b) L)^-1 diag(b) ---
// block = bh*32 + chunk. C=64. S = K K^T (hi/lo MFMA), T unit-lower,
// invert by forward recurrence (64 lanes = columns), W out as bf16 hi/lo.
__global__ __launch_bounds__(256) void wprep_kernel(
    const float* __restrict__ Km, const float* __restrict__ beta,
    unsigned short* __restrict__ Whi, unsigned short* __restrict__ Wlo) {
  __shared__ unsigned short Khi[64 * 256];   // [t][n] rows 512B, swz ((t&7)<<4)
  __shared__ unsigned short Klo[64 * 256];
  __shared__ float Bm[64 * 64];              // Bm[t][s] = b_t * L[t][s] (strict lower)
  __shared__ float X[64 * 64];               // T^-1
  __shared__ float bv[64];
  int blk = blockIdx.x, ch = blk & 31, bh = blk >> 5;
  int b = bh >> 3, h = bh & 7;
  int t0 = ch * 64;
  int tid = threadIdx.x, wave = tid >> 6, lane = tid & 63;
  int khi = lane >> 4, l16 = lane & 15;
  {
    int t = tid >> 2, n0 = (tid & 3) * 64;
    const float* kp = Km + ((long)(b * TSEQ) + t0 + t) * 256 + n0;
    char* ph = (char*)Khi + t * 512;
    char* pl = (char*)Klo + t * 512;
#pragma unroll
    for (int i = 0; i < 64; i += 8) {
      float4 v0 = *(const float4*)(kp + i);
      float4 v1 = *(const float4*)(kp + i + 4);
      float vv[8] = {v0.x, v0.y, v0.z, v0.w, v1.x, v1.y, v1.z, v1.w};
      unsigned int hw[4], lw[4];
#pragma unroll
      for (int q = 0; q < 4; ++q) {
        unsigned short h0 = f2bf(vv[2 * q]), h1 = f2bf(vv[2 * q + 1]);
        hw[q] = (unsigned)h0 | ((unsigned)h1 << 16);
        lw[q] = (unsigned)f2bf(vv[2 * q] - bf2f(h0)) |
                ((unsigned)f2bf(vv[2 * q + 1] - bf2f(h1)) << 16);
      }
      int off = ((n0 + i) * 2) ^ ((t & 7) << 4);
      *(uint4*)(ph + off) = make_uint4(hw[0], hw[1], hw[2], hw[3]);
      *(uint4*)(pl + off) = make_uint4(lw[0], lw[1], lw[2], lw[3]);
    }
  }
  if (tid < 64) bv[tid] = beta[((long)(b * TSEQ) + t0 + tid) * 8 + h];
  __syncthreads();
  // S = K K^T: wave = t-tile, 4 s-tiles
  f32x4 sacc[4] = {};
#pragma unroll
  for (int ks = 0; ks < 8; ++ks) {
    int arow = wave * 16 + l16;
    int koff = (ks * 32 + khi * 8) * 2;
    bf16x8 ah = *(const bf16x8*)((const char*)Khi + arow * 512 + (koff ^ ((arow & 7) << 4)));
    bf16x8 al = *(const bf16x8*)((const char*)Klo + arow * 512 + (koff ^ ((arow & 7) << 4)));
    bf16x8 bhf[4], blf[4];
#pragma unroll
    for (int si = 0; si < 4; ++si) {
      int brow = si * 16 + l16;
      bhf[si] = *(const bf16x8*)((const char*)Khi + brow * 512 + (koff ^ ((brow & 7) << 4)));
      blf[si] = *(const bf16x8*)((const char*)Klo + brow * 512 + (koff ^ ((brow & 7) << 4)));
    }
#pragma unroll
    for (int si = 0; si < 4; ++si) sacc[si] = mfma16(ah, bhf[si], sacc[si]);
#pragma unroll
    for (int si = 0; si < 4; ++si) sacc[si] = mfma16(ah, blf[si], sacc[si]);
#pragma unroll
    for (int si = 0; si < 4; ++si) sacc[si] = mfma16(al, bhf[si], sacc[si]);
  }
#pragma unroll
  for (int si = 0; si < 4; ++si)
#pragma unroll
    for (int r = 0; r < 4; ++r) {
      int t = wave * 16 + khi * 4 + r, s = si * 16 + l16;
      Bm[t * 64 + s] = (s < t) ? bv[t] * sacc[si][r] : 0.f;
    }
  __syncthreads();
  if (wave == 0) {
    // X row t: X[t][s] = delta(t,s) - sum_{r<t} Bm[t][r] X[r][s]; lane = s.
    for (int t = 0; t < 64; ++t) {
      float xv = (lane == t) ? 1.f : 0.f;
      for (int r = 0; r < t; ++r)
        xv = fmaf(-Bm[t * 64 + r], X[r * 64 + lane], xv);
      X[t * 64 + lane] = xv;
    }
  }
  __syncthreads();
  long base = (long)blk * 4096;
  for (int i = tid; i < 4096; i += 256) {
    int s = i & 63;
    float wv = X[i] * bv[s];
    unsigned short hi = f2bf(wv);
    Whi[base + i] = hi;
    Wlo[base + i] = f2bf(wv - bf2f(hi));
  }
}

// ---------------- Kernel 5b: chunked scan, M in MFMA accumulators -------
// 256 blocks = 32 bh x 8 d-slices(64). 4 waves. Per chunk (32 serial):
//   A = Kr*(Mhi+Mlo); R = V - A; U = (Wh+Wl)*R; M += Kr^T*(Uhi+Ulo).
__global__ __launch_bounds__(256) void cscan_kernel(
    const float* __restrict__ Km, const float* __restrict__ xn,
    const float* __restrict__ M0,
    const unsigned short* __restrict__ Whi, const unsigned short* __restrict__ Wlo,
    float* __restrict__ Mout) {
  __shared__ unsigned short Mthi[64 * 256];  // [d][n] rows 512B, swz ((d&7)<<4)
  __shared__ unsigned short Mtlo[64 * 256];
  __shared__ unsigned short Kr[64 * 256];    // [t][n] rows 512B, swz KSW(t)
  __shared__ unsigned short Wh[64 * 64];     // [t][s] rows 128B, swz ((t&7)<<4)
  __shared__ unsigned short Wl[64 * 64];
  __shared__ unsigned short RU0[64 * 64];    // [d][t] rows 128B, swz ((d&7)<<4)
  __shared__ unsigned short RU1[64 * 64];
  int blk = blockIdx.x, dsl = blk & 7, bh = blk >> 3;
  int b = bh >> 3;
  int d0 = dsl * 64;
  int tid = threadIdx.x, wave = tid >> 6, lane = tid & 63;
  int khi = lane >> 4, l16 = lane & 15;

  // M accumulators: wave owns n in [wave*64, wave*64+64): 4 n-tiles x 4 d-tiles
  f32x4 macc[4][4];
  const float* M0p = M0 + (long)bh * 256 * 512;
#pragma unroll
  for (int ni = 0; ni < 4; ++ni)
#pragma unroll
    for (int di = 0; di < 4; ++di)
#pragma unroll
      for (int r = 0; r < 4; ++r) {
        int n = wave * 64 + ni * 16 + khi * 4 + r;
        macc[ni][di][r] = M0p[(long)n * 512 + d0 + di * 16 + l16];
      }

  // write Mt hi/lo
#pragma unroll
  for (int ni = 0; ni < 4; ++ni)
#pragma unroll
    for (int di = 0; di < 4; ++di) {
      int n = wave * 64 + ni * 16 + khi * 4;
      int d = di * 16 + l16;
      unsigned short hq[4], lq[4];
#pragma unroll
      for (int r = 0; r < 4; ++r) {
        float v = macc[ni][di][r];
        hq[r] = f2bf(v); lq[r] = f2bf(v - bf2f(hq[r]));
      }
      int off = d * 512 + (((n * 2) ^ ((d & 7) << 4)));
      *(uint2*)((char*)Mthi + off) =
          make_uint2((unsigned)hq[0] | ((unsigned)hq[1] << 16),
                     (unsigned)hq[2] | ((unsigned)hq[3] << 16));
      *(uint2*)((char*)Mtlo + off) =
          make_uint2((unsigned)lq[0] | ((unsigned)lq[1] << 16),
                     (unsigned)lq[2] | ((unsigned)lq[3] << 16));
    }
  __syncthreads();

  for (int ch = 0; ch < 32; ++ch) {
    int tc0 = ch * 64;
    // ---- stage Kr (bf16 hi) ----
    {
      int t = tid >> 2, n0q = (tid & 3) * 64;
      const float* kp = Km + ((long)(b * TSEQ) + tc0 + t) * 256 + n0q;
      char* ph = (char*)Kr + t * 512;
#pragma unroll
      for (int i = 0; i < 64; i += 8) {
        float4 v0 = *(const float4*)(kp + i);
        float4 v1 = *(const float4*)(kp + i + 4);
        unsigned int hw[4];
        hw[0] = (unsigned)f2bf(v0.x) | ((unsigned)f2bf(v0.y) << 16);
        hw[1] = (unsigned)f2bf(v0.z) | ((unsigned)f2bf(v0.w) << 16);
        hw[2] = (unsigned)f2bf(v1.x) | ((unsigned)f2bf(v1.y) << 16);
        hw[3] = (unsigned)f2bf(v1.z) | ((unsigned)f2bf(v1.w) << 16);
        int off = ((n0q + i) * 2) ^ KSW(t);
        *(uint4*)(ph + off) = make_uint4(hw[0], hw[1], hw[2], hw[3]);
      }
    }
    // ---- stage W hi/lo ----
    {
      long wbase = ((long)bh * 32 + ch) * 4096;
      int i = tid * 16;
      int t = i >> 6, s = i & 63;
      int o1 = t * 128 + (((s * 2) ^ ((t & 7) << 4)));
      int o2 = t * 128 + ((((s + 8) * 2) ^ ((t & 7) << 4)));
      *(uint4*)((char*)Wh + o1) = *(const uint4*)(Whi + wbase + i);
      *(uint4*)((char*)Wh + o2) = *(const uint4*)(Whi + wbase + i + 8);
      *(uint4*)((char*)Wl + o1) = *(const uint4*)(Wlo + wbase + i);
      *(uint4*)((char*)Wl + o2) = *(const uint4*)(Wlo + wbase + i + 8);
    }
    // ---- prefetch V (16 f32) ----
    float vreg[4][4];
    {
      const float* vp = xn + ((long)b * TSEQ + tc0) * 512 + d0;
#pragma unroll
      for (int di = 0; di < 4; ++di)
#pragma unroll
        for (int r = 0; r < 4; ++r) {
          int t = wave * 16 + khi * 4 + r;
          vreg[di][r] = vp[(long)t * 512 + di * 16 + l16];
        }
    }
    __syncthreads();  // b1: Kr, W staged

    // ---- A = Kr * (Mthi + Mtlo): wave = t-tile ----
    f32x4 aacc[4] = {};
#pragma unroll
    for (int ks = 0; ks < 8; ++ks) {
      int arow = wave * 16 + l16;
      int koff = (ks * 32 + khi * 8) * 2;
      bf16x8 af = *(const bf16x8*)((const char*)Kr + arow * 512 + (koff ^ KSW(arow)));
      bf16x8 mh[4], ml[4];
#pragma unroll
      for (int di = 0; di < 4; ++di) {
        int drow = di * 16 + l16;
        mh[di] = *(const bf16x8*)((const char*)Mthi + drow * 512 + (koff ^ ((drow & 7) << 4)));
        ml[di] = *(const bf16x8*)((const char*)Mtlo + drow * 512 + (koff ^ ((drow & 7) << 4)));
      }
#pragma unroll
      for (int di = 0; di < 4; ++di) aacc[di] = mfma16(af, mh[di], aacc[di]);
#pragma unroll
      for (int di = 0; di < 4; ++di) aacc[di] = mfma16(af, ml[di], aacc[di]);
    }
    // ---- R = V - A -> RU0 (bf16 hi) ----
#pragma unroll
    for (int di = 0; di < 4; ++di) {
      int t = wave * 16 + khi * 4;
      int d = di * 16 + l16;
      unsigned short rq[4];
#pragma unroll
      for (int r = 0; r < 4; ++r) rq[r] = f2bf(vreg[di][r] - aacc[di][r]);
      int off = d * 128 + (((t * 2) ^ ((d & 7) << 4)));
      *(uint2*)((char*)RU0 + off) =
          make_uint2((unsigned)rq[0] | ((unsigned)rq[1] << 16),
                     (unsigned)rq[2] | ((unsigned)rq[3] << 16));
    }
    __syncthreads();  // b2: R ready

    // ---- U = (Wh + Wl) * R: wave = t-tile ----
    f32x4 uacc[4] = {};
#pragma unroll
    for (int ks = 0; ks < 2; ++ks) {
      int arow = wave * 16 + l16;
      int soff = (ks * 32 + khi * 8) * 2;
      bf16x8 wh_ = *(const bf16x8*)((const char*)Wh + arow * 128 + (soff ^ ((arow & 7) << 4)));
      bf16x8 wl_ = *(const bf16x8*)((const char*)Wl + arow * 128 + (soff ^ ((arow & 7) << 4)));
      bf16x8 rf[4];
#pragma unroll
      for (int di = 0; di < 4; ++di) {
        int drow = di * 16 + l16;
        rf[di] = *(const bf16x8*)((const char*)RU0 + drow * 128 + (soff ^ ((drow & 7) << 4)));
      }
#pragma unroll
      for (int di = 0; di < 4; ++di) uacc[di] = mfma16(wh_, rf[di], uacc[di]);
#pragma unroll
      for (int di = 0; di < 4; ++di) uacc[di] = mfma16(wl_, rf[di], uacc[di]);
    }
    __syncthreads();  // b3: RU0 free

    // ---- write Ut hi/lo ----
#pragma unroll
    for (int di = 0; di < 4; ++di) {
      int t = wave * 16 + khi * 4;
      int d = di * 16 + l16;
      unsigned short hq[4], lq[4];
#pragma unroll
      for (int r = 0; r < 4; ++r) {
        float u = uacc[di][r];
        hq[r] = f2bf(u); lq[r] = f2bf(u - bf2f(hq[r]));
      }
      int off = d * 128 + (((t * 2) ^ ((d & 7) << 4)));
      *(uint2*)((char*)RU0 + off) =
          make_uint2((unsigned)hq[0] | ((unsigned)hq[1] << 16),
                     (unsigned)hq[2] | ((unsigned)hq[3] << 16));
      *(uint2*)((char*)RU1 + off) =
          make_uint2((unsigned)lq[0] | ((unsigned)lq[1] << 16),
                     (unsigned)lq[2] | ((unsigned)lq[3] << 16));
    }
    __syncthreads();  // b4: Ut ready

    // ---- M += Kr^T * (Uhi + Ulo): wave = n-range ----
#pragma unroll
    for (int ks = 0; ks < 2; ++ks) {
      bf16x8 ka[4];
#pragma unroll
      for (int ni = 0; ni < 4; ++ni) {
        int n = wave * 64 + ni * 16 + l16;
        bf16x8 kv;
#pragma unroll
        for (int j = 0; j < 8; ++j) {
          int t = ks * 32 + khi * 8 + j;
          kv[j] = *(const short*)((const char*)Kr + t * 512 + (((n * 2) ^ KSW(t))));
        }
        ka[ni] = kv;
      }
      bf16x8 uh[4], ul[4];
#pragma unroll
      for (int di = 0; di < 4; ++di) {
        int drow = di * 16 + l16;
        int toff = (ks * 32 + khi * 8) * 2;
        uh[di] = *(const bf16x8*)((const char*)RU0 + drow * 128 + (toff ^ ((drow & 7) << 4)));
        ul[di] = *(const bf16x8*)((const char*)RU1 + drow * 128 + (toff ^ ((drow & 7) << 4)));
      }
#pragma unroll
      for (int ni = 0; ni < 4; ++ni)
#pragma unroll
        for (int di = 0; di < 4; ++di)
          macc[ni][di] = mfma16(ka[ni], uh[di], macc[ni][di]);
#pragma unroll
      for (int ni = 0; ni < 4; ++ni)
#pragma unroll
        for (int di = 0; di < 4; ++di)
          macc[ni][di] = mfma16(ka[ni], ul[di], macc[ni][di]);
    }
    __syncthreads();  // b5: all reads of Kr/RU/Mt done

    // ---- rewrite Mt hi/lo ----
#pragma unroll
    for (int ni = 0; ni < 4; ++ni)
#pragma unroll
      for (int di = 0; di < 4; ++di) {
        int n = wave * 64 + ni * 16 + khi * 4;
        int d = di * 16 + l16;
        unsigned short hq[4], lq[4];
#pragma unroll
        for (int r = 0; r < 4; ++r) {
          float v = macc[ni][di][r];
          hq[r] = f2bf(v); lq[r] = f2bf(v - bf2f(hq[r]));
        }
        int off = d * 512 + (((n * 2) ^ ((d & 7) << 4)));
        *(uint2*)((char*)Mthi + off) =
            make_uint2((unsigned)hq[0] | ((unsigned)hq[1] << 16),
                       (unsigned)hq[2] | ((unsigned)hq[3] << 16));
        *(uint2*)((char*)Mtlo + off) =
            make_uint2((unsigned)lq[0] | ((unsigned)lq[1] << 16),
                       (unsigned)lq[2] | ((unsigned)lq[3] << 16));
      }
    __syncthreads();  // b6: Mt ready for next chunk
  }

  float* Mo = Mout + (long)bh * 256 * 512;
#pragma unroll
  for (int ni = 0; ni < 4; ++ni)
#pragma unroll
    for (int di = 0; di < 4; ++di)
#pragma unroll
      for (int r = 0; r < 4; ++r) {
        int n = wave * 64 + ni * 16 + khi * 4 + r;
        Mo[(long)n * 512 + d0 + di * 16 + l16] = macc[ni][di][r];
      }
}

// ---------------- Kernel 6: causal attention y_standard -----------------
__global__ __launch_bounds__(512) void attn_kernel(
    const unsigned short* __restrict__ QR,
    const unsigned short* __restrict__ Vt,
    float* __restrict__ Y) {
  int bt = blockIdx.x;
  int bh = blockIdx.y;
  int dch = blockIdx.z;
  int t0 = bt * 128, d0 = dch * 256;
  int wave = threadIdx.x >> 6, lane = threadIdx.x & 63;
  int wr = wave >> 2, wc = wave & 3;
  int khi = lane >> 4, l16 = lane & 15;
  __shared__ unsigned short K_lds[64 * 256];
  __shared__ unsigned short S_lds[128 * 64];
  const unsigned short* QRb = QR + (long)bh * TSEQ * 256;
  const unsigned short* Vtb = Vt + (long)bh * 512 * TSEQ;
  bf16x8 qa[8];
  {
    int trow = t0 + wave * 16 + l16;
    const unsigned short* qp = QRb + (long)trow * 256 + khi * 8;
#pragma unroll
    for (int ks = 0; ks < 8; ++ks) qa[ks] = *reinterpret_cast<const bf16x8*>(qp + ks * 32);
  }
  f32x4 acc[4][4] = {};
  int nst = bt * 2 + 2;
  for (int st = 0; st < nst; ++st) {
    int s0 = st * 64;
#pragma unroll
    for (int p = 0; p < 4; ++p) {
      int row = (threadIdx.x >> 5) + p * 16;
      int nc = (threadIdx.x & 31) * 8;
      bf16x8 v = *reinterpret_cast<const bf16x8*>(QRb + (long)(s0 + row) * 256 + nc);
      *reinterpret_cast<bf16x8*>((char*)K_lds + row * 512 + ((nc * 2) ^ ((row & 7) << 4))) = v;
    }
    __syncthreads();
    f32x4 sacc[4] = {};
#pragma unroll
    for (int ks = 0; ks < 8; ++ks) {
#pragma unroll
      for (int fc = 0; fc < 4; ++fc) {
        int srow = fc * 16 + l16;
        bf16x8 kf = *reinterpret_cast<const bf16x8*>(
            (const char*)K_lds + srow * 512 + ((ks * 64 + khi * 16) ^ ((srow & 7) << 4)));
        sacc[fc] = mfma16(qa[ks], kf, sacc[fc]);
      }
    }
#pragma unroll
    for (int fc = 0; fc < 4; ++fc)
#pragma unroll
      for (int r = 0; r < 4; ++r) {
        int srow = wave * 16 + khi * 4 + r;
        int scol = fc * 16 + l16;
        float v = ((s0 + scol) < (t0 + srow)) ? sacc[fc][r] : 0.f;
        *reinterpret_cast<unsigned short*>(
            (char*)S_lds + srow * 128 + ((scol * 2) ^ ((srow & 7) << 4))) = f2bf(v);
      }
    __syncthreads();
#pragma unroll
    for (int k2 = 0; k2 < 2; ++k2) {
      bf16x8 af[4], bfv[4];
#pragma unroll
      for (int mi = 0; mi < 4; ++mi) {
        int row = wr * 64 + mi * 16 + l16;
        af[mi] = *reinterpret_cast<const bf16x8*>(
            (const char*)S_lds + row * 128 + ((k2 * 64 + khi * 16) ^ ((row & 7) << 4)));
      }
#pragma unroll
      for (int ni = 0; ni < 4; ++ni) {
        int d = d0 + wc * 64 + ni * 16 + l16;
        bfv[ni] = *reinterpret_cast<const bf16x8*>(Vtb + (long)d * TSEQ + s0 + k2 * 32 + khi * 8);
      }
#pragma unroll
      for (int mi = 0; mi < 4; ++mi)
#pragma unroll
        for (int ni = 0; ni < 4; ++ni)
          acc[mi][ni] = mfma16(af[mi], bfv[ni], acc[mi][ni]);
    }
    __syncthreads();
  }
  float* yb = Y + (long)bh * TSEQ * 512;
#pragma unroll
  for (int mi = 0; mi < 4; ++mi)
#pragma unroll
    for (int ni = 0; ni < 4; ++ni)
#pragma unroll
      for (int r = 0; r < 4; ++r) {
        int trow = t0 + wr * 64 + mi * 16 + khi * 4 + r;
        int d = d0 + wc * 64 + ni * 16 + l16;
        yb[(long)trow * 512 + d] = acc[mi][ni][r];
      }
}

// ---------------- Kernel 7: y_memory GEMM + LN + gated combine ----------
__global__ __launch_bounds__(512) void combine_kernel(
    const unsigned short* __restrict__ Qm,
    const unsigned short* __restrict__ M0t,
    const float* __restrict__ mg,
    float* __restrict__ Y) {
  int t0 = blockIdx.x * 64;
  int bh = blockIdx.y;
  int b = bh >> 3, h = bh & 7;
  int wv = threadIdx.x >> 6, lane = threadIdx.x & 63;
  int khi = lane >> 4, l16 = lane & 15;
  __shared__ unsigned short A_lds[64 * 256];
  __shared__ float red_s[8][64], red_q[8][64];
  __shared__ float mu_s[64], inv_s[64];
  {
    const unsigned short* src = Qm + ((long)b * TSEQ + t0) * 256;
#pragma unroll
    for (int p = 0; p < 4; ++p) {
      int row = (threadIdx.x >> 5) + p * 16;
      int nc = (threadIdx.x & 31) * 8;
      bf16x8 v = *reinterpret_cast<const bf16x8*>(src + (long)row * 256 + nc);
      *reinterpret_cast<bf16x8*>((char*)A_lds + row * 512 + ((nc * 2) ^ ((row & 7) << 4))) = v;
    }
  }
  __syncthreads();
  f32x4 acc[4][4] = {};
  const unsigned short* Bp = M0t + (long)bh * 512 * 256;
#pragma unroll
  for (int ks = 0; ks < 8; ++ks) {
    bf16x8 a[4], bfr[4];
#pragma unroll
    for (int mi = 0; mi < 4; ++mi) {
      int row = mi * 16 + l16;
      a[mi] = *reinterpret_cast<const bf16x8*>(
          (const char*)A_lds + row * 512 + ((ks * 64 + khi * 16) ^ ((row & 7) << 4)));
    }
#pragma unroll
    for (int ni = 0; ni < 4; ++ni) {
      int d = wv * 64 + ni * 16 + l16;
      bfr[ni] = *reinterpret_cast<const bf16x8*>(Bp + (long)d * 256 + ks * 32 + khi * 8);
    }
#pragma unroll
    for (int mi = 0; mi < 4; ++mi)
#pragma unroll
      for (int ni = 0; ni < 4; ++ni)
        acc[mi][ni] = mfma16(a[mi], bfr[ni], acc[mi][ni]);
  }
  float ps[4][4], pq[4][4];
#pragma unroll
  for (int mi = 0; mi < 4; ++mi)
#pragma unroll
    for (int r = 0; r < 4; ++r) {
      float s = 0.f, q = 0.f;
#pragma unroll
      for (int ni = 0; ni < 4; ++ni) {
        float v = acc[mi][ni][r];
        s += v; q += v * v;
      }
      ps[mi][r] = s; pq[mi][r] = q;
    }
#pragma unroll
  for (int off = 1; off < 16; off <<= 1)
#pragma unroll
    for (int mi = 0; mi < 4; ++mi)
#pragma unroll
      for (int r = 0; r < 4; ++r) {
        ps[mi][r] += __shfl_xor(ps[mi][r], off);
        pq[mi][r] += __shfl_xor(pq[mi][r], off);
      }
  if (l16 == 0) {
#pragma unroll
    for (int mi = 0; mi < 4; ++mi)
#pragma unroll
      for (int r = 0; r < 4; ++r) {
        int row = mi * 16 + khi * 4 + r;
        red_s[wv][row] = ps[mi][r];
        red_q[wv][row] = pq[mi][r];
      }
  }
  __syncthreads();
  if (threadIdx.x < 64) {
    float s = 0.f, q = 0.f;
#pragma unroll
    for (int w2 = 0; w2 < 8; ++w2) { s += red_s[w2][threadIdx.x]; q += red_q[w2][threadIdx.x]; }
    float mu = s / 512.f;
    float var = q / 512.f - mu * mu;
    mu_s[threadIdx.x] = mu;
    inv_s[threadIdx.x] = rsqrtf(var + 1e-5f);
  }
  __syncthreads();
  float gate = 1.f / (1.f + expf(-mg[h]));
  float omg = 1.f - gate;
  float* yb = Y + ((long)bh * TSEQ + t0) * 512;
#pragma unroll
  for (int mi = 0; mi < 4; ++mi)
#pragma unroll
    for (int r = 0; r < 4; ++r) {
      int row = mi * 16 + khi * 4 + r;
      float mu = mu_s[row], inv = inv_s[row];
#pragma unroll
      for (int ni = 0; ni < 4; ++ni) {
        int d = wv * 64 + ni * 16 + l16;
        long off = (long)row * 512 + d;
        float ymv = (acc[mi][ni][r] - mu) * inv;
        yb[off] = omg * yb[off] + gate * ymv;
      }
    }
}

// ---------------- host launcher -----------------------------------------
extern "C" void kernel_launch(void* const* d_in, const int* in_sizes, int n_in,
                              void* d_out, int out_size, void* d_ws, size_t ws_size,
                              hipStream_t stream) {
  const float* Q      = (const float*)d_in[0];
  const float* V      = (const float*)d_in[1];
  const float* x_raw  = (const float*)d_in[2];
  const float* x_next = (const float*)d_in[3];
  const float* wq     = (const float*)d_in[4];
  const float* wk     = (const float*)d_in[5];
  const float* bw     = (const float*)d_in[6];
  const float* mg     = (const float*)d_in[7];
  const float* M0     = (const float*)d_in[8];
  float* y = (float*)d_out;
  float* Mout = y + (long)32 * 2048 * 512;

  char* ws = (char*)d_ws;
  unsigned short* QR  = (unsigned short*)(ws);                 // 33,554,432 B
  unsigned short* Vt  = (unsigned short*)(ws + 33554432);      // 67,108,864 B
  unsigned short* M0t = (unsigned short*)(ws + 100663296);     //  8,388,608 B
  unsigned short* Qm  = (unsigned short*)(ws + 109051904);     //  4,194,304 B
  float*  Km          = (float*)(ws + 113246208);              //  8,388,608 B
  float*  beta        = (float*)(ws + 121634816);              //    262,144 B
  // W buffers alias the Vt region (Vt is written only after cscan is done)
  unsigned short* Whi = (unsigned short*)(ws + 33554432);      //  8,388,608 B
  unsigned short* Wlo = (unsigned short*)(ws + 41943040);      //  8,388,608 B

  qkm_kernel<<<dim3(128, 2), dim3(512), 0, stream>>>(x_raw, wq, wk, Qm, Km);
  beta_kernel<<<dim3(8192), dim3(64), 0, stream>>>(x_raw, bw, beta);
  wprep_kernel<<<dim3(1024), dim3(256), 0, stream>>>(Km, beta, Whi, Wlo);
  cscan_kernel<<<dim3(256), dim3(256), 0, stream>>>(Km, x_next, M0, Whi, Wlo, Mout);
  rope_kernel<<<dim3(32768), dim3(256), 0, stream>>>(Q, QR);
  transpose_cast_kernel<<<dim3(8, 32, 32), dim3(256), 0, stream>>>(V, Vt, 2048, 512);
  transpose_cast_kernel<<<dim3(8, 4, 32), dim3(256), 0, stream>>>(M0, M0t, 256, 512);
  attn_kernel<<<dim3(16, 32, 2), dim3(512), 0, stream>>>(QR, Vt, y);
  combine_kernel<<<dim3(32, 32), dim3(512), 0, stream>>>(Qm, M0t, mg, y);
}

// Round 7
// 853.154 us; speedup vs baseline: 5.0570x; 1.2666x over previous
//
#include <hip/hip_runtime.h>
#include <hip/hip_bf16.h>
#include <math.h>

#define BBATCH 4
#define NHEAD  8
#define TSEQ   2048
#define NDIM   256
#define DDIM   512

typedef float f32x4 __attribute__((ext_vector_type(4)));
typedef short bf16x8 __attribute__((ext_vector_type(8)));

typedef __attribute__((address_space(3))) unsigned int lds_uint;
typedef __attribute__((address_space(1))) unsigned int g_uint;

__device__ __forceinline__ unsigned short f2bf(float f) {
  __hip_bfloat16 h = __float2bfloat16(f);
  return *reinterpret_cast<unsigned short*>(&h);
}
__device__ __forceinline__ float bf2f(unsigned short u) {
  __hip_bfloat16 h;
  *reinterpret_cast<unsigned short*>(&h) = u;
  return __bfloat162float(h);
}
__device__ __forceinline__ f32x4 mfma16(bf16x8 a, bf16x8 b, f32x4 c) {
  return __builtin_amdgcn_mfma_f32_16x16x32_bf16(a, b, c, 0, 0, 0);
}

// Kr swizzle (two-level, spreads both row-low and row-mid bits)
#define KSW(t) (((((t) & 7) ^ (((t) >> 3) & 3))) << 4)

// ---------------- Kernel 1: RoPE(Q) -> QR bf16 --------------------------
__global__ __launch_bounds__(256) void rope_kernel(const float* __restrict__ Q,
                                                   unsigned short* __restrict__ QR) {
  long idx = (long)blockIdx.x * 256 + threadIdx.x;
  int pair = (int)(idx & 127);
  long row = idx >> 7;
  int t = (int)(row & (TSEQ - 1));
  float2 q = reinterpret_cast<const float2*>(Q)[idx];
  float freq = exp2f(-(float)pair * 0.125f) * 0.15915494309189535f;
  float phase = (float)t * freq;
  float ph = (phase - floorf(phase)) * 6.283185307179586f;
  float s, c;
  sincosf(ph, &s, &c);
  float o0 = q.x * c - q.y * s;
  float o1 = q.y * c + q.x * s;
  unsigned int pk = (unsigned int)f2bf(o0) | ((unsigned int)f2bf(o1) << 16);
  reinterpret_cast<unsigned int*>(QR)[idx] = pk;
}

// ---------------- Kernel 2: transpose + cast f32[R][C] -> bf16[C][R] ----
__global__ __launch_bounds__(256) void transpose_cast_kernel(
    const float* __restrict__ in, unsigned short* __restrict__ out, int R, int C) {
  __shared__ float tile[64][65];
  long mat = blockIdx.z;
  const float* src = in + mat * (long)R * C;
  unsigned short* dst = out + mat * (long)R * C;
  int c0 = blockIdx.x * 64, r0 = blockIdx.y * 64;
  int tr = threadIdx.x >> 4;
  int tc = (threadIdx.x & 15) * 4;
#pragma unroll
  for (int p = 0; p < 4; ++p) {
    int r = tr + p * 16;
    float4 v = *reinterpret_cast<const float4*>(&src[(long)(r0 + r) * C + c0 + tc]);
    tile[r][tc + 0] = v.x; tile[r][tc + 1] = v.y;
    tile[r][tc + 2] = v.z; tile[r][tc + 3] = v.w;
  }
  __syncthreads();
#pragma unroll
  for (int p = 0; p < 4; ++p) {
    int c = tr + p * 16;
    ushort4 o;
    o.x = f2bf(tile[tc + 0][c]);
    o.y = f2bf(tile[tc + 1][c]);
    o.z = f2bf(tile[tc + 2][c]);
    o.w = f2bf(tile[tc + 3][c]);
    *reinterpret_cast<ushort4*>(&dst[(long)(c0 + c) * R + r0 + tc]) = o;
  }
}

// ---------------- Kernel 3: Qm/Km = l2norm(x @ W^T), bf16x3-split MFMA --
__global__ __launch_bounds__(512) void qkm_kernel(
    const float* __restrict__ x,
    const float* __restrict__ wq,
    const float* __restrict__ wk,
    unsigned short* __restrict__ Qm,
    float* __restrict__ Km) {
  const bool isK = (blockIdx.y == 1);
  const float* w = isK ? wk : wq;
  int r0 = blockIdx.x * 64;
  int wave = threadIdx.x >> 6, lane = threadIdx.x & 63;
  int wm = wave >> 2, wn = wave & 3;
  int khi = lane >> 4, l16 = lane & 15;
  __shared__ unsigned short Ahi[64 * 32], Alo[64 * 32];
  __shared__ unsigned short Bhi[256 * 32], Blo[256 * 32];
  __shared__ float red[4][64];
  f32x4 acc[2][4] = {};
  for (int k0 = 0; k0 < 512; k0 += 32) {
    {
      int row = threadIdx.x >> 3;
      int kc = (threadIdx.x & 7) * 4;
      float4 v = *reinterpret_cast<const float4*>(&x[(long)(r0 + row) * 512 + k0 + kc]);
      float vv[4] = {v.x, v.y, v.z, v.w};
      unsigned int hx[2], lx[2];
      unsigned short h0 = f2bf(vv[0]), h1 = f2bf(vv[1]), h2 = f2bf(vv[2]), h3 = f2bf(vv[3]);
      hx[0] = (unsigned)h0 | ((unsigned)h1 << 16);
      hx[1] = (unsigned)h2 | ((unsigned)h3 << 16);
      lx[0] = (unsigned)f2bf(vv[0] - bf2f(h0)) | ((unsigned)f2bf(vv[1] - bf2f(h1)) << 16);
      lx[1] = (unsigned)f2bf(vv[2] - bf2f(h2)) | ((unsigned)f2bf(vv[3] - bf2f(h3)) << 16);
      int byt = row * 64 + ((kc * 2) ^ ((row & 3) << 4));
      *reinterpret_cast<uint2*>((char*)Ahi + byt) = make_uint2(hx[0], hx[1]);
      *reinterpret_cast<uint2*>((char*)Alo + byt) = make_uint2(lx[0], lx[1]);
    }
#pragma unroll
    for (int p = 0; p < 4; ++p) {
      int idx2 = threadIdx.x + p * 512;
      int row = idx2 >> 3;
      int kc = (idx2 & 7) * 4;
      float4 v = *reinterpret_cast<const float4*>(&w[(long)row * 512 + k0 + kc]);
      float vv[4] = {v.x, v.y, v.z, v.w};
      unsigned short h0 = f2bf(vv[0]), h1 = f2bf(vv[1]), h2 = f2bf(vv[2]), h3 = f2bf(vv[3]);
      unsigned int hx0 = (unsigned)h0 | ((unsigned)h1 << 16);
      unsigned int hx1 = (unsigned)h2 | ((unsigned)h3 << 16);
      unsigned int lx0 = (unsigned)f2bf(vv[0] - bf2f(h0)) | ((unsigned)f2bf(vv[1] - bf2f(h1)) << 16);
      unsigned int lx1 = (unsigned)f2bf(vv[2] - bf2f(h2)) | ((unsigned)f2bf(vv[3] - bf2f(h3)) << 16);
      int byt = row * 64 + ((kc * 2) ^ ((row & 3) << 4));
      *reinterpret_cast<uint2*>((char*)Bhi + byt) = make_uint2(hx0, hx1);
      *reinterpret_cast<uint2*>((char*)Blo + byt) = make_uint2(lx0, lx1);
    }
    __syncthreads();
    bf16x8 ah[2], al[2], bh[4], bl[4];
#pragma unroll
    for (int mi = 0; mi < 2; ++mi) {
      int row = wm * 32 + mi * 16 + l16;
      int byt = row * 64 + ((khi * 16) ^ ((row & 3) << 4));
      ah[mi] = *reinterpret_cast<const bf16x8*>((const char*)Ahi + byt);
      al[mi] = *reinterpret_cast<const bf16x8*>((const char*)Alo + byt);
    }
#pragma unroll
    for (int ni = 0; ni < 4; ++ni) {
      int row = wn * 64 + ni * 16 + l16;
      int byt = row * 64 + ((khi * 16) ^ ((row & 3) << 4));
      bh[ni] = *reinterpret_cast<const bf16x8*>((const char*)Bhi + byt);
      bl[ni] = *reinterpret_cast<const bf16x8*>((const char*)Blo + byt);
    }
#pragma unroll
    for (int mi = 0; mi < 2; ++mi)
#pragma unroll
      for (int ni = 0; ni < 4; ++ni) {
        acc[mi][ni] = mfma16(ah[mi], bh[ni], acc[mi][ni]);
        acc[mi][ni] = mfma16(ah[mi], bl[ni], acc[mi][ni]);
        acc[mi][ni] = mfma16(al[mi], bh[ni], acc[mi][ni]);
      }
    __syncthreads();
  }
  float part[2][4];
#pragma unroll
  for (int mi = 0; mi < 2; ++mi)
#pragma unroll
    for (int r = 0; r < 4; ++r) {
      float s = 0.f;
#pragma unroll
      for (int ni = 0; ni < 4; ++ni) s += acc[mi][ni][r] * acc[mi][ni][r];
      part[mi][r] = s;
    }
#pragma unroll
  for (int off = 1; off < 16; off <<= 1)
#pragma unroll
    for (int mi = 0; mi < 2; ++mi)
#pragma unroll
      for (int r = 0; r < 4; ++r) part[mi][r] += __shfl_xor(part[mi][r], off);
  if (l16 == 0) {
#pragma unroll
    for (int mi = 0; mi < 2; ++mi)
#pragma unroll
      for (int r = 0; r < 4; ++r)
        red[wn][wm * 32 + mi * 16 + khi * 4 + r] = part[mi][r];
  }
  __syncthreads();
#pragma unroll
  for (int mi = 0; mi < 2; ++mi)
#pragma unroll
    for (int r = 0; r < 4; ++r) {
      int row = wm * 32 + mi * 16 + khi * 4 + r;
      float ss = red[0][row] + red[1][row] + red[2][row] + red[3][row];
      float scale = 1.f / fmaxf(sqrtf(ss), 1e-12f);
#pragma unroll
      for (int ni = 0; ni < 4; ++ni) {
        int col = wn * 64 + ni * 16 + l16;
        float val = acc[mi][ni][r] * scale;
        if (isK) Km[(long)(r0 + row) * 256 + col] = val;
        else     Qm[(long)(r0 + row) * 256 + col] = f2bf(val);
      }
    }
}

// ---------------- Kernel 4: beta = sigmoid(x @ beta_w^T) ----------------
__global__ __launch_bounds__(64) void beta_kernel(const float* __restrict__ x,
                                                  const float* __restrict__ bw,
                                                  float* __restrict__ beta) {
  long row = blockIdx.x;
  int lane = threadIdx.x;
  const float* xr = x + row * 512;
  float xv[8];
#pragma unroll
  for (int j = 0; j < 8; ++j) xv[j] = xr[lane + j * 64];
#pragma unroll
  for (int hh = 0; hh < 8; ++hh) {
    const float* wr = bw + hh * 512;
    float p = 0.f;
#pragma unroll
    for (int j = 0; j < 8; ++j) p += xv[j] * wr[lane + j * 64];
#pragma unroll
    for (int off = 32; off > 0; off >>= 1) p += __shfl_down(p, off);
    if (lane == 0) beta[row * 8 + hh] = 1.f / (1.f + expf(-p));
  }
}

// ---------------- Kernel 5a: per-chunk W = (I + diag(b) L)^-1 diag(b) ---
__global__ __launch_bounds__(256) void wprep_kernel(
    const float* __restrict__ Km, const float* __restrict__ beta,
    unsigned short* __restrict__ Whi, unsigned short* __restrict__ Wlo) {
  __shared__ unsigned short Khi[64 * 256];
  __shared__ unsigned short Klo[64 * 256];
  __shared__ float Bm[64 * 64];
  __shared__ float X[64 * 64];
  __shared__ float bv[64];
  int blk = blockIdx.x, ch = blk & 31, bh = blk >> 5;
  int b = bh >> 3, h = bh & 7;
  int t0 = ch * 64;
  int tid = threadIdx.x, wave = tid >> 6, lane = tid & 63;
  int khi = lane >> 4, l16 = lane & 15;
  {
    int t = tid >> 2, n0 = (tid & 3) * 64;
    const float* kp = Km + ((long)(b * TSEQ) + t0 + t) * 256 + n0;
    char* ph = (char*)Khi + t * 512;
    char* pl = (char*)Klo + t * 512;
#pragma unroll
    for (int i = 0; i < 64; i += 8) {
      float4 v0 = *(const float4*)(kp + i);
      float4 v1 = *(const float4*)(kp + i + 4);
      float vv[8] = {v0.x, v0.y, v0.z, v0.w, v1.x, v1.y, v1.z, v1.w};
      unsigned int hw[4], lw[4];
#pragma unroll
      for (int q = 0; q < 4; ++q) {
        unsigned short h0 = f2bf(vv[2 * q]), h1 = f2bf(vv[2 * q + 1]);
        hw[q] = (unsigned)h0 | ((unsigned)h1 << 16);
        lw[q] = (unsigned)f2bf(vv[2 * q] - bf2f(h0)) |
                ((unsigned)f2bf(vv[2 * q + 1] - bf2f(h1)) << 16);
      }
      int off = ((n0 + i) * 2) ^ ((t & 7) << 4);
      *(uint4*)(ph + off) = make_uint4(hw[0], hw[1], hw[2], hw[3]);
      *(uint4*)(pl + off) = make_uint4(lw[0], lw[1], lw[2], lw[3]);
    }
  }
  if (tid < 64) bv[tid] = beta[((long)(b * TSEQ) + t0 + tid) * 8 + h];
  __syncthreads();
  f32x4 sacc[4] = {};
#pragma unroll
  for (int ks = 0; ks < 8; ++ks) {
    int arow = wave * 16 + l16;
    int koff = (ks * 32 + khi * 8) * 2;
    bf16x8 ah = *(const bf16x8*)((const char*)Khi + arow * 512 + (koff ^ ((arow & 7) << 4)));
    bf16x8 al = *(const bf16x8*)((const char*)Klo + arow * 512 + (koff ^ ((arow & 7) << 4)));
    bf16x8 bhf[4], blf[4];
#pragma unroll
    for (int si = 0; si < 4; ++si) {
      int brow = si * 16 + l16;
      bhf[si] = *(const bf16x8*)((const char*)Khi + brow * 512 + (koff ^ ((brow & 7) << 4)));
      blf[si] = *(const bf16x8*)((const char*)Klo + brow * 512 + (koff ^ ((brow & 7) << 4)));
    }
#pragma unroll
    for (int si = 0; si < 4; ++si) sacc[si] = mfma16(ah, bhf[si], sacc[si]);
#pragma unroll
    for (int si = 0; si < 4; ++si) sacc[si] = mfma16(ah, blf[si], sacc[si]);
#pragma unroll
    for (int si = 0; si < 4; ++si) sacc[si] = mfma16(al, bhf[si], sacc[si]);
  }
#pragma unroll
  for (int si = 0; si < 4; ++si)
#pragma unroll
    for (int r = 0; r < 4; ++r) {
      int t = wave * 16 + khi * 4 + r, s = si * 16 + l16;
      Bm[t * 64 + s] = (s < t) ? bv[t] * sacc[si][r] : 0.f;
    }
  __syncthreads();
  if (wave == 0) {
    for (int t = 0; t < 64; ++t) {
      float xv = (lane == t) ? 1.f : 0.f;
      for (int r = 0; r < t; ++r)
        xv = fmaf(-Bm[t * 64 + r], X[r * 64 + lane], xv);
      X[t * 64 + lane] = xv;
    }
  }
  __syncthreads();
  long base = (long)blk * 4096;
  for (int i = tid; i < 4096; i += 256) {
    int s = i & 63;
    float wv = X[i] * bv[s];
    unsigned short hi = f2bf(wv);
    Whi[base + i] = hi;
    Wlo[base + i] = f2bf(wv - bf2f(hi));
  }
}

// ---------------- Kernel 5b: chunked scan, M in MFMA accumulators -------
__global__ __launch_bounds__(256) void cscan_kernel(
    const float* __restrict__ Km, const float* __restrict__ xn,
    const float* __restrict__ M0,
    const unsigned short* __restrict__ Whi, const unsigned short* __restrict__ Wlo,
    float* __restrict__ Mout) {
  __shared__ unsigned short Mthi[64 * 256];
  __shared__ unsigned short Mtlo[64 * 256];
  __shared__ unsigned short Kr[64 * 256];
  __shared__ unsigned short Wh[64 * 64];
  __shared__ unsigned short Wl[64 * 64];
  __shared__ unsigned short RU0[64 * 64];
  __shared__ unsigned short RU1[64 * 64];
  int blk = blockIdx.x, dsl = blk & 7, bh = blk >> 3;
  int b = bh >> 3;
  int d0 = dsl * 64;
  int tid = threadIdx.x, wave = tid >> 6, lane = tid & 63;
  int khi = lane >> 4, l16 = lane & 15;

  f32x4 macc[4][4];
  const float* M0p = M0 + (long)bh * 256 * 512;
#pragma unroll
  for (int ni = 0; ni < 4; ++ni)
#pragma unroll
    for (int di = 0; di < 4; ++di)
#pragma unroll
      for (int r = 0; r < 4; ++r) {
        int n = wave * 64 + ni * 16 + khi * 4 + r;
        macc[ni][di][r] = M0p[(long)n * 512 + d0 + di * 16 + l16];
      }

#pragma unroll
  for (int ni = 0; ni < 4; ++ni)
#pragma unroll
    for (int di = 0; di < 4; ++di) {
      int n = wave * 64 + ni * 16 + khi * 4;
      int d = di * 16 + l16;
      unsigned short hq[4], lq[4];
#pragma unroll
      for (int r = 0; r < 4; ++r) {
        float v = macc[ni][di][r];
        hq[r] = f2bf(v); lq[r] = f2bf(v - bf2f(hq[r]));
      }
      int off = d * 512 + (((n * 2) ^ ((d & 7) << 4)));
      *(uint2*)((char*)Mthi + off) =
          make_uint2((unsigned)hq[0] | ((unsigned)hq[1] << 16),
                     (unsigned)hq[2] | ((unsigned)hq[3] << 16));
      *(uint2*)((char*)Mtlo + off) =
          make_uint2((unsigned)lq[0] | ((unsigned)lq[1] << 16),
                     (unsigned)lq[2] | ((unsigned)lq[3] << 16));
    }
  __syncthreads();

  for (int ch = 0; ch < 32; ++ch) {
    int tc0 = ch * 64;
    {
      int t = tid >> 2, n0q = (tid & 3) * 64;
      const float* kp = Km + ((long)(b * TSEQ) + tc0 + t) * 256 + n0q;
      char* ph = (char*)Kr + t * 512;
#pragma unroll
      for (int i = 0; i < 64; i += 8) {
        float4 v0 = *(const float4*)(kp + i);
        float4 v1 = *(const float4*)(kp + i + 4);
        unsigned int hw[4];
        hw[0] = (unsigned)f2bf(v0.x) | ((unsigned)f2bf(v0.y) << 16);
        hw[1] = (unsigned)f2bf(v0.z) | ((unsigned)f2bf(v0.w) << 16);
        hw[2] = (unsigned)f2bf(v1.x) | ((unsigned)f2bf(v1.y) << 16);
        hw[3] = (unsigned)f2bf(v1.z) | ((unsigned)f2bf(v1.w) << 16);
        int off = ((n0q + i) * 2) ^ KSW(t);
        *(uint4*)(ph + off) = make_uint4(hw[0], hw[1], hw[2], hw[3]);
      }
    }
    {
      long wbase = ((long)bh * 32 + ch) * 4096;
      int i = tid * 16;
      int t = i >> 6, s = i & 63;
      int o1 = t * 128 + (((s * 2) ^ ((t & 7) << 4)));
      int o2 = t * 128 + ((((s + 8) * 2) ^ ((t & 7) << 4)));
      *(uint4*)((char*)Wh + o1) = *(const uint4*)(Whi + wbase + i);
      *(uint4*)((char*)Wh + o2) = *(const uint4*)(Whi + wbase + i + 8);
      *(uint4*)((char*)Wl + o1) = *(const uint4*)(Wlo + wbase + i);
      *(uint4*)((char*)Wl + o2) = *(const uint4*)(Wlo + wbase + i + 8);
    }
    float vreg[4][4];
    {
      const float* vp = xn + ((long)b * TSEQ + tc0) * 512 + d0;
#pragma unroll
      for (int di = 0; di < 4; ++di)
#pragma unroll
        for (int r = 0; r < 4; ++r) {
          int t = wave * 16 + khi * 4 + r;
          vreg[di][r] = vp[(long)t * 512 + di * 16 + l16];
        }
    }
    __syncthreads();

    f32x4 aacc[4] = {};
#pragma unroll
    for (int ks = 0; ks < 8; ++ks) {
      int arow = wave * 16 + l16;
      int koff = (ks * 32 + khi * 8) * 2;
      bf16x8 af = *(const bf16x8*)((const char*)Kr + arow * 512 + (koff ^ KSW(arow)));
      bf16x8 mh[4], ml[4];
#pragma unroll
      for (int di = 0; di < 4; ++di) {
        int drow = di * 16 + l16;
        mh[di] = *(const bf16x8*)((const char*)Mthi + drow * 512 + (koff ^ ((drow & 7) << 4)));
        ml[di] = *(const bf16x8*)((const char*)Mtlo + drow * 512 + (koff ^ ((drow & 7) << 4)));
      }
#pragma unroll
      for (int di = 0; di < 4; ++di) aacc[di] = mfma16(af, mh[di], aacc[di]);
#pragma unroll
      for (int di = 0; di < 4; ++di) aacc[di] = mfma16(af, ml[di], aacc[di]);
    }
#pragma unroll
    for (int di = 0; di < 4; ++di) {
      int t = wave * 16 + khi * 4;
      int d = di * 16 + l16;
      unsigned short rq[4];
#pragma unroll
      for (int r = 0; r < 4; ++r) rq[r] = f2bf(vreg[di][r] - aacc[di][r]);
      int off = d * 128 + (((t * 2) ^ ((d & 7) << 4)));
      *(uint2*)((char*)RU0 + off) =
          make_uint2((unsigned)rq[0] | ((unsigned)rq[1] << 16),
                     (unsigned)rq[2] | ((unsigned)rq[3] << 16));
    }
    __syncthreads();

    f32x4 uacc[4] = {};
#pragma unroll
    for (int ks = 0; ks < 2; ++ks) {
      int arow = wave * 16 + l16;
      int soff = (ks * 32 + khi * 8) * 2;
      bf16x8 wh_ = *(const bf16x8*)((const char*)Wh + arow * 128 + (soff ^ ((arow & 7) << 4)));
      bf16x8 wl_ = *(const bf16x8*)((const char*)Wl + arow * 128 + (soff ^ ((arow & 7) << 4)));
      bf16x8 rf[4];
#pragma unroll
      for (int di = 0; di < 4; ++di) {
        int drow = di * 16 + l16;
        rf[di] = *(const bf16x8*)((const char*)RU0 + drow * 128 + (soff ^ ((drow & 7) << 4)));
      }
#pragma unroll
      for (int di = 0; di < 4; ++di) uacc[di] = mfma16(wh_, rf[di], uacc[di]);
#pragma unroll
      for (int di = 0; di < 4; ++di) uacc[di] = mfma16(wl_, rf[di], uacc[di]);
    }
    __syncthreads();

#pragma unroll
    for (int di = 0; di < 4; ++di) {
      int t = wave * 16 + khi * 4;
      int d = di * 16 + l16;
      unsigned short hq[4], lq[4];
#pragma unroll
      for (int r = 0; r < 4; ++r) {
        float u = uacc[di][r];
        hq[r] = f2bf(u); lq[r] = f2bf(u - bf2f(hq[r]));
      }
      int off = d * 128 + (((t * 2) ^ ((d & 7) << 4)));
      *(uint2*)((char*)RU0 + off) =
          make_uint2((unsigned)hq[0] | ((unsigned)hq[1] << 16),
                     (unsigned)hq[2] | ((unsigned)hq[3] << 16));
      *(uint2*)((char*)RU1 + off) =
          make_uint2((unsigned)lq[0] | ((unsigned)lq[1] << 16),
                     (unsigned)lq[2] | ((unsigned)lq[3] << 16));
    }
    __syncthreads();

#pragma unroll
    for (int ks = 0; ks < 2; ++ks) {
      bf16x8 ka[4];
#pragma unroll
      for (int ni = 0; ni < 4; ++ni) {
        int n = wave * 64 + ni * 16 + l16;
        bf16x8 kv;
#pragma unroll
        for (int j = 0; j < 8; ++j) {
          int t = ks * 32 + khi * 8 + j;
          kv[j] = *(const short*)((const char*)Kr + t * 512 + (((n * 2) ^ KSW(t))));
        }
        ka[ni] = kv;
      }
      bf16x8 uh[4], ul[4];
#pragma unroll
      for (int di = 0; di < 4; ++di) {
        int drow = di * 16 + l16;
        int toff = (ks * 32 + khi * 8) * 2;
        uh[di] = *(const bf16x8*)((const char*)RU0 + drow * 128 + (toff ^ ((drow & 7) << 4)));
        ul[di] = *(const bf16x8*)((const char*)RU1 + drow * 128 + (toff ^ ((drow & 7) << 4)));
      }
#pragma unroll
      for (int ni = 0; ni < 4; ++ni)
#pragma unroll
        for (int di = 0; di < 4; ++di)
          macc[ni][di] = mfma16(ka[ni], uh[di], macc[ni][di]);
#pragma unroll
      for (int ni = 0; ni < 4; ++ni)
#pragma unroll
        for (int di = 0; di < 4; ++di)
          macc[ni][di] = mfma16(ka[ni], ul[di], macc[ni][di]);
    }
    __syncthreads();

#pragma unroll
    for (int ni = 0; ni < 4; ++ni)
#pragma unroll
      for (int di = 0; di < 4; ++di) {
        int n = wave * 64 + ni * 16 + khi * 4;
        int d = di * 16 + l16;
        unsigned short hq[4], lq[4];
#pragma unroll
        for (int r = 0; r < 4; ++r) {
          float v = macc[ni][di][r];
          hq[r] = f2bf(v); lq[r] = f2bf(v - bf2f(hq[r]));
        }
        int off = d * 512 + (((n * 2) ^ ((d & 7) << 4)));
        *(uint2*)((char*)Mthi + off) =
            make_uint2((unsigned)hq[0] | ((unsigned)hq[1] << 16),
                       (unsigned)hq[2] | ((unsigned)hq[3] << 16));
        *(uint2*)((char*)Mtlo + off) =
            make_uint2((unsigned)lq[0] | ((unsigned)lq[1] << 16),
                       (unsigned)lq[2] | ((unsigned)lq[3] << 16));
      }
    __syncthreads();
  }

  float* Mo = Mout + (long)bh * 256 * 512;
#pragma unroll
  for (int ni = 0; ni < 4; ++ni)
#pragma unroll
    for (int di = 0; di < 4; ++di)
#pragma unroll
      for (int r = 0; r < 4; ++r) {
        int n = wave * 64 + ni * 16 + khi * 4 + r;
        Mo[(long)n * 512 + d0 + di * 16 + l16] = macc[ni][di][r];
      }
}

// ---------------- Kernel 6: causal attention y_standard (v2) ------------
// Pairing: block bp handles t-tiles bt=15-bp then bt=bp -> uniform 34 iters.
// 2 barriers/iter; K staged via global_load_lds (inverse-swizzled source),
// prefetch for st+1 issued during PV so the latency hides under MFMA.
__global__ __launch_bounds__(512) void attn_kernel(
    const unsigned short* __restrict__ QR,
    const unsigned short* __restrict__ Vt,
    float* __restrict__ Y) {
  int bp = blockIdx.x;     // 0..7
  int bh = blockIdx.y;
  int dch = blockIdx.z;
  int wave = threadIdx.x >> 6, lane = threadIdx.x & 63;
  int wr = wave >> 2, wc = wave & 3;
  int khi = lane >> 4, l16 = lane & 15;
  __shared__ unsigned short K_lds[64 * 256];  // 32KB, swizzled
  __shared__ unsigned short S_lds[128 * 64];  // 16KB, swizzled
  const unsigned short* QRb = QR + (long)bh * TSEQ * 256;
  const unsigned short* Vtb = Vt + (long)bh * 512 * TSEQ;
  int d0 = dch * 256;
  float* yb = Y + (long)bh * TSEQ * 512;

  // linear LDS chunk -> inverse-swizzled global source (rule #21 pattern)
  int lin_base = wave * 4096 + lane * 16;      // + q*1024

#pragma unroll 1
  for (int half = 0; half < 2; ++half) {
    int bt = half ? bp : (15 - bp);
    int t0 = bt * 128;
    int nst = 2 * bt + 2;

    bf16x8 qa[8];
    {
      int trow = t0 + wave * 16 + l16;
      const unsigned short* qp = QRb + (long)trow * 256 + khi * 8;
#pragma unroll
      for (int ks = 0; ks < 8; ++ks) qa[ks] = *(const bf16x8*)(qp + ks * 32);
    }
    f32x4 acc[4][4] = {};

    // prologue: stage K tile st=0
#pragma unroll
    for (int q = 0; q < 4; ++q) {
      int linear = lin_base + q * 1024;
      int row = linear >> 9;
      int nc2 = (linear & 511) ^ ((row & 7) << 4);
      __builtin_amdgcn_global_load_lds(
          (const g_uint*)((const char*)QRb + (long)row * 512 + nc2),
          (lds_uint*)((char*)K_lds + (wave * 4 + q) * 1024), 16, 0, 0);
    }
    __syncthreads();

    for (int st = 0; st < nst; ++st) {
      int s0 = st * 64;
      // phase 1: S = Q K^T
      f32x4 sacc[4] = {};
#pragma unroll
      for (int ks = 0; ks < 8; ++ks) {
#pragma unroll
        for (int fc = 0; fc < 4; ++fc) {
          int srow = fc * 16 + l16;
          bf16x8 kf = *(const bf16x8*)(
              (const char*)K_lds + srow * 512 + ((ks * 64 + khi * 16) ^ ((srow & 7) << 4)));
          sacc[fc] = mfma16(qa[ks], kf, sacc[fc]);
        }
      }
      // mask (strict lower) + cast + store S
#pragma unroll
      for (int fc = 0; fc < 4; ++fc)
#pragma unroll
        for (int r = 0; r < 4; ++r) {
          int srow = wave * 16 + khi * 4 + r;
          int scol = fc * 16 + l16;
          float v = ((s0 + scol) < (t0 + srow)) ? sacc[fc][r] : 0.f;
          *(unsigned short*)(
              (char*)S_lds + srow * 128 + ((scol * 2) ^ ((srow & 7) << 4))) = f2bf(v);
        }
      __syncthreads();   // b2: S ready, all phase-1 K_lds reads done

      // prefetch next K tile directly into K_lds (async; drains at b1)
      if (st + 1 < nst) {
        long srow_base = (long)(s0 + 64) * 512;
#pragma unroll
        for (int q = 0; q < 4; ++q) {
          int linear = lin_base + q * 1024;
          int row = linear >> 9;
          int nc2 = (linear & 511) ^ ((row & 7) << 4);
          __builtin_amdgcn_global_load_lds(
              (const g_uint*)((const char*)QRb + srow_base + (long)row * 512 + nc2),
              (lds_uint*)((char*)K_lds + (wave * 4 + q) * 1024), 16, 0, 0);
        }
      }
      // phase 2: O += S @ V
#pragma unroll
      for (int k2 = 0; k2 < 2; ++k2) {
        bf16x8 af[4], bfv[4];
#pragma unroll
        for (int mi = 0; mi < 4; ++mi) {
          int row = wr * 64 + mi * 16 + l16;
          af[mi] = *(const bf16x8*)(
              (const char*)S_lds + row * 128 + ((k2 * 64 + khi * 16) ^ ((row & 7) << 4)));
        }
#pragma unroll
        for (int ni = 0; ni < 4; ++ni) {
          int d = d0 + wc * 64 + ni * 16 + l16;
          bfv[ni] = *(const bf16x8*)(Vtb + (long)d * TSEQ + s0 + k2 * 32 + khi * 8);
        }
#pragma unroll
        for (int mi = 0; mi < 4; ++mi)
#pragma unroll
          for (int ni = 0; ni < 4; ++ni)
            acc[mi][ni] = mfma16(af[mi], bfv[ni], acc[mi][ni]);
      }
      __syncthreads();   // b1: K_lds[st+1] landed (vmcnt drain), S_lds reads done
    }

    // write Y for this half
#pragma unroll
    for (int mi = 0; mi < 4; ++mi)
#pragma unroll
      for (int ni = 0; ni < 4; ++ni)
#pragma unroll
        for (int r = 0; r < 4; ++r) {
          int trow = t0 + wr * 64 + mi * 16 + khi * 4 + r;
          int d = d0 + wc * 64 + ni * 16 + l16;
          yb[(long)trow * 512 + d] = acc[mi][ni][r];
        }
  }
}

// ---------------- Kernel 7: y_memory GEMM + LN + gated combine ----------
__global__ __launch_bounds__(512) void combine_kernel(
    const unsigned short* __restrict__ Qm,
    const unsigned short* __restrict__ M0t,
    const float* __restrict__ mg,
    float* __restrict__ Y) {
  int t0 = blockIdx.x * 64;
  int bh = blockIdx.y;
  int b = bh >> 3, h = bh & 7;
  int wv = threadIdx.x >> 6, lane = threadIdx.x & 63;
  int khi = lane >> 4, l16 = lane & 15;
  __shared__ unsigned short A_lds[64 * 256];
  __shared__ float red_s[8][64], red_q[8][64];
  __shared__ float mu_s[64], inv_s[64];
  {
    const unsigned short* src = Qm + ((long)b * TSEQ + t0) * 256;
#pragma unroll
    for (int p = 0; p < 4; ++p) {
      int row = (threadIdx.x >> 5) + p * 16;
      int nc = (threadIdx.x & 31) * 8;
      bf16x8 v = *reinterpret_cast<const bf16x8*>(src + (long)row * 256 + nc);
      *reinterpret_cast<bf16x8*>((char*)A_lds + row * 512 + ((nc * 2) ^ ((row & 7) << 4))) = v;
    }
  }
  __syncthreads();
  f32x4 acc[4][4] = {};
  const unsigned short* Bp = M0t + (long)bh * 512 * 256;
#pragma unroll
  for (int ks = 0; ks < 8; ++ks) {
    bf16x8 a[4], bfr[4];
#pragma unroll
    for (int mi = 0; mi < 4; ++mi) {
      int row = mi * 16 + l16;
      a[mi] = *reinterpret_cast<const bf16x8*>(
          (const char*)A_lds + row * 512 + ((ks * 64 + khi * 16) ^ ((row & 7) << 4)));
    }
#pragma unroll
    for (int ni = 0; ni < 4; ++ni) {
      int d = wv * 64 + ni * 16 + l16;
      bfr[ni] = *reinterpret_cast<const bf16x8*>(Bp + (long)d * 256 + ks * 32 + khi * 8);
    }
#pragma unroll
    for (int mi = 0; mi < 4; ++mi)
#pragma unroll
      for (int ni = 0; ni < 4; ++ni)
        acc[mi][ni] = mfma16(a[mi], bfr[ni], acc[mi][ni]);
  }
  float ps[4][4], pq[4][4];
#pragma unroll
  for (int mi = 0; mi < 4; ++mi)
#pragma unroll
    for (int r = 0; r < 4; ++r) {
      float s = 0.f, q = 0.f;
#pragma unroll
      for (int ni = 0; ni < 4; ++ni) {
        float v = acc[mi][ni][r];
        s += v; q += v * v;
      }
      ps[mi][r] = s; pq[mi][r] = q;
    }
#pragma unroll
  for (int off = 1; off < 16; off <<= 1)
#pragma unroll
    for (int mi = 0; mi < 4; ++mi)
#pragma unroll
      for (int r = 0; r < 4; ++r) {
        ps[mi][r] += __shfl_xor(ps[mi][r], off);
        pq[mi][r] += __shfl_xor(pq[mi][r], off);
      }
  if (l16 == 0) {
#pragma unroll
    for (int mi = 0; mi < 4; ++mi)
#pragma unroll
      for (int r = 0; r < 4; ++r) {
        int row = mi * 16 + khi * 4 + r;
        red_s[wv][row] = ps[mi][r];
        red_q[wv][row] = pq[mi][r];
      }
  }
  __syncthreads();
  if (threadIdx.x < 64) {
    float s = 0.f, q = 0.f;
#pragma unroll
    for (int w2 = 0; w2 < 8; ++w2) { s += red_s[w2][threadIdx.x]; q += red_q[w2][threadIdx.x]; }
    float mu = s / 512.f;
    float var = q / 512.f - mu * mu;
    mu_s[threadIdx.x] = mu;
    inv_s[threadIdx.x] = rsqrtf(var + 1e-5f);
  }
  __syncthreads();
  float gate = 1.f / (1.f + expf(-mg[h]));
  float omg = 1.f - gate;
  float* yb = Y + ((long)bh * TSEQ + t0) * 512;
#pragma unroll
  for (int mi = 0; mi < 4; ++mi)
#pragma unroll
    for (int r = 0; r < 4; ++r) {
      int row = mi * 16 + khi * 4 + r;
      float mu = mu_s[row], inv = inv_s[row];
#pragma unroll
      for (int ni = 0; ni < 4; ++ni) {
        int d = wv * 64 + ni * 16 + l16;
        long off = (long)row * 512 + d;
        float ymv = (acc[mi][ni][r] - mu) * inv;
        yb[off] = omg * yb[off] + gate * ymv;
      }
    }
}

// ---------------- host launcher -----------------------------------------
extern "C" void kernel_launch(void* const* d_in, const int* in_sizes, int n_in,
                              void* d_out, int out_size, void* d_ws, size_t ws_size,
                              hipStream_t stream) {
  const float* Q      = (const float*)d_in[0];
  const float* V      = (const float*)d_in[1];
  const float* x_raw  = (const float*)d_in[2];
  const float* x_next = (const float*)d_in[3];
  const float* wq     = (const float*)d_in[4];
  const float* wk     = (const float*)d_in[5];
  const float* bw     = (const float*)d_in[6];
  const float* mg     = (const float*)d_in[7];
  const float* M0     = (const float*)d_in[8];
  float* y = (float*)d_out;
  float* Mout = y + (long)32 * 2048 * 512;

  char* ws = (char*)d_ws;
  unsigned short* QR  = (unsigned short*)(ws);                 // 33,554,432 B
  unsigned short* Vt  = (unsigned short*)(ws + 33554432);      // 67,108,864 B
  unsigned short* M0t = (unsigned short*)(ws + 100663296);     //  8,388,608 B
  unsigned short* Qm  = (unsigned short*)(ws + 109051904);     //  4,194,304 B
  float*  Km          = (float*)(ws + 113246208);              //  8,388,608 B
  float*  beta        = (float*)(ws + 121634816);              //    262,144 B
  // W buffers alias the Vt region (Vt is written only after cscan is done)
  unsigned short* Whi = (unsigned short*)(ws + 33554432);      //  8,388,608 B
  unsigned short* Wlo = (unsigned short*)(ws + 41943040);      //  8,388,608 B

  qkm_kernel<<<dim3(128, 2), dim3(512), 0, stream>>>(x_raw, wq, wk, Qm, Km);
  beta_kernel<<<dim3(8192), dim3(64), 0, stream>>>(x_raw, bw, beta);
  wprep_kernel<<<dim3(1024), dim3(256), 0, stream>>>(Km, beta, Whi, Wlo);
  cscan_kernel<<<dim3(256), dim3(256), 0, stream>>>(Km, x_next, M0, Whi, Wlo, Mout);
  rope_kernel<<<dim3(32768), dim3(256), 0, stream>>>(Q, QR);
  transpose_cast_kernel<<<dim3(8, 32, 32), dim3(256), 0, stream>>>(V, Vt, 2048, 512);
  transpose_cast_kernel<<<dim3(8, 4, 32), dim3(256), 0, stream>>>(M0, M0t, 256, 512);
  attn_kernel<<<dim3(8, 32, 2), dim3(512), 0, stream>>>(QR, Vt, y);
  combine_kernel<<<dim3(32, 32), dim3(512), 0, stream>>>(Qm, M0t, mg, y);
}

// Round 8
// 707.967 us; speedup vs baseline: 6.0940x; 1.2051x over previous
//
#include <hip/hip_runtime.h>
#include <hip/hip_bf16.h>
#include <math.h>

#define BBATCH 4
#define NHEAD  8
#define TSEQ   2048
#define NDIM   256
#define DDIM   512

typedef float f32x4 __attribute__((ext_vector_type(4)));
typedef short bf16x8 __attribute__((ext_vector_type(8)));

typedef __attribute__((address_space(3))) unsigned int lds_uint;
typedef __attribute__((address_space(1))) unsigned int g_uint;

__device__ __forceinline__ unsigned short f2bf(float f) {
  __hip_bfloat16 h = __float2bfloat16(f);
  return *reinterpret_cast<unsigned short*>(&h);
}
__device__ __forceinline__ float bf2f(unsigned short u) {
  __hip_bfloat16 h;
  *reinterpret_cast<unsigned short*>(&h) = u;
  return __bfloat162float(h);
}
__device__ __forceinline__ f32x4 mfma16(bf16x8 a, bf16x8 b, f32x4 c) {
  return __builtin_amdgcn_mfma_f32_16x16x32_bf16(a, b, c, 0, 0, 0);
}

// Kr swizzle (two-level, spreads both row-low and row-mid bits)
#define KSW(t) (((((t) & 7) ^ (((t) >> 3) & 3))) << 4)

// ---------------- Kernel 1: RoPE(Q) -> QR bf16 --------------------------
__global__ __launch_bounds__(256) void rope_kernel(const float* __restrict__ Q,
                                                   unsigned short* __restrict__ QR) {
  long idx = (long)blockIdx.x * 256 + threadIdx.x;
  int pair = (int)(idx & 127);
  long row = idx >> 7;
  int t = (int)(row & (TSEQ - 1));
  float2 q = reinterpret_cast<const float2*>(Q)[idx];
  float freq = exp2f(-(float)pair * 0.125f) * 0.15915494309189535f;
  float phase = (float)t * freq;
  float ph = (phase - floorf(phase)) * 6.283185307179586f;
  float s, c;
  sincosf(ph, &s, &c);
  float o0 = q.x * c - q.y * s;
  float o1 = q.y * c + q.x * s;
  unsigned int pk = (unsigned int)f2bf(o0) | ((unsigned int)f2bf(o1) << 16);
  reinterpret_cast<unsigned int*>(QR)[idx] = pk;
}

// ---------------- Kernel 2: transpose + cast f32[R][C] -> bf16[C][R] ----
__global__ __launch_bounds__(256) void transpose_cast_kernel(
    const float* __restrict__ in, unsigned short* __restrict__ out, int R, int C) {
  __shared__ float tile[64][65];
  long mat = blockIdx.z;
  const float* src = in + mat * (long)R * C;
  unsigned short* dst = out + mat * (long)R * C;
  int c0 = blockIdx.x * 64, r0 = blockIdx.y * 64;
  int tr = threadIdx.x >> 4;
  int tc = (threadIdx.x & 15) * 4;
#pragma unroll
  for (int p = 0; p < 4; ++p) {
    int r = tr + p * 16;
    float4 v = *reinterpret_cast<const float4*>(&src[(long)(r0 + r) * C + c0 + tc]);
    tile[r][tc + 0] = v.x; tile[r][tc + 1] = v.y;
    tile[r][tc + 2] = v.z; tile[r][tc + 3] = v.w;
  }
  __syncthreads();
#pragma unroll
  for (int p = 0; p < 4; ++p) {
    int c = tr + p * 16;
    ushort4 o;
    o.x = f2bf(tile[tc + 0][c]);
    o.y = f2bf(tile[tc + 1][c]);
    o.z = f2bf(tile[tc + 2][c]);
    o.w = f2bf(tile[tc + 3][c]);
    *reinterpret_cast<ushort4*>(&dst[(long)(c0 + c) * R + r0 + tc]) = o;
  }
}

// ---------------- Kernel 3: Qm/Km = l2norm(x @ W^T), bf16x3-split MFMA --
__global__ __launch_bounds__(512) void qkm_kernel(
    const float* __restrict__ x,
    const float* __restrict__ wq,
    const float* __restrict__ wk,
    unsigned short* __restrict__ Qm,
    float* __restrict__ Km,
    unsigned short* __restrict__ Kmb) {
  const bool isK = (blockIdx.y == 1);
  const float* w = isK ? wk : wq;
  int r0 = blockIdx.x * 64;
  int wave = threadIdx.x >> 6, lane = threadIdx.x & 63;
  int wm = wave >> 2, wn = wave & 3;
  int khi = lane >> 4, l16 = lane & 15;
  __shared__ unsigned short Ahi[64 * 32], Alo[64 * 32];
  __shared__ unsigned short Bhi[256 * 32], Blo[256 * 32];
  __shared__ float red[4][64];
  f32x4 acc[2][4] = {};
  for (int k0 = 0; k0 < 512; k0 += 32) {
    {
      int row = threadIdx.x >> 3;
      int kc = (threadIdx.x & 7) * 4;
      float4 v = *reinterpret_cast<const float4*>(&x[(long)(r0 + row) * 512 + k0 + kc]);
      float vv[4] = {v.x, v.y, v.z, v.w};
      unsigned int hx[2], lx[2];
      unsigned short h0 = f2bf(vv[0]), h1 = f2bf(vv[1]), h2 = f2bf(vv[2]), h3 = f2bf(vv[3]);
      hx[0] = (unsigned)h0 | ((unsigned)h1 << 16);
      hx[1] = (unsigned)h2 | ((unsigned)h3 << 16);
      lx[0] = (unsigned)f2bf(vv[0] - bf2f(h0)) | ((unsigned)f2bf(vv[1] - bf2f(h1)) << 16);
      lx[1] = (unsigned)f2bf(vv[2] - bf2f(h2)) | ((unsigned)f2bf(vv[3] - bf2f(h3)) << 16);
      int byt = row * 64 + ((kc * 2) ^ ((row & 3) << 4));
      *reinterpret_cast<uint2*>((char*)Ahi + byt) = make_uint2(hx[0], hx[1]);
      *reinterpret_cast<uint2*>((char*)Alo + byt) = make_uint2(lx[0], lx[1]);
    }
#pragma unroll
    for (int p = 0; p < 4; ++p) {
      int idx2 = threadIdx.x + p * 512;
      int row = idx2 >> 3;
      int kc = (idx2 & 7) * 4;
      float4 v = *reinterpret_cast<const float4*>(&w[(long)row * 512 + k0 + kc]);
      float vv[4] = {v.x, v.y, v.z, v.w};
      unsigned short h0 = f2bf(vv[0]), h1 = f2bf(vv[1]), h2 = f2bf(vv[2]), h3 = f2bf(vv[3]);
      unsigned int hx0 = (unsigned)h0 | ((unsigned)h1 << 16);
      unsigned int hx1 = (unsigned)h2 | ((unsigned)h3 << 16);
      unsigned int lx0 = (unsigned)f2bf(vv[0] - bf2f(h0)) | ((unsigned)f2bf(vv[1] - bf2f(h1)) << 16);
      unsigned int lx1 = (unsigned)f2bf(vv[2] - bf2f(h2)) | ((unsigned)f2bf(vv[3] - bf2f(h3)) << 16);
      int byt = row * 64 + ((kc * 2) ^ ((row & 3) << 4));
      *reinterpret_cast<uint2*>((char*)Bhi + byt) = make_uint2(hx0, hx1);
      *reinterpret_cast<uint2*>((char*)Blo + byt) = make_uint2(lx0, lx1);
    }
    __syncthreads();
    bf16x8 ah[2], al[2], bh[4], bl[4];
#pragma unroll
    for (int mi = 0; mi < 2; ++mi) {
      int row = wm * 32 + mi * 16 + l16;
      int byt = row * 64 + ((khi * 16) ^ ((row & 3) << 4));
      ah[mi] = *reinterpret_cast<const bf16x8*>((const char*)Ahi + byt);
      al[mi] = *reinterpret_cast<const bf16x8*>((const char*)Alo + byt);
    }
#pragma unroll
    for (int ni = 0; ni < 4; ++ni) {
      int row = wn * 64 + ni * 16 + l16;
      int byt = row * 64 + ((khi * 16) ^ ((row & 3) << 4));
      bh[ni] = *reinterpret_cast<const bf16x8*>((const char*)Bhi + byt);
      bl[ni] = *reinterpret_cast<const bf16x8*>((const char*)Blo + byt);
    }
#pragma unroll
    for (int mi = 0; mi < 2; ++mi)
#pragma unroll
      for (int ni = 0; ni < 4; ++ni) {
        acc[mi][ni] = mfma16(ah[mi], bh[ni], acc[mi][ni]);
        acc[mi][ni] = mfma16(ah[mi], bl[ni], acc[mi][ni]);
        acc[mi][ni] = mfma16(al[mi], bh[ni], acc[mi][ni]);
      }
    __syncthreads();
  }
  float part[2][4];
#pragma unroll
  for (int mi = 0; mi < 2; ++mi)
#pragma unroll
    for (int r = 0; r < 4; ++r) {
      float s = 0.f;
#pragma unroll
      for (int ni = 0; ni < 4; ++ni) s += acc[mi][ni][r] * acc[mi][ni][r];
      part[mi][r] = s;
    }
#pragma unroll
  for (int off = 1; off < 16; off <<= 1)
#pragma unroll
    for (int mi = 0; mi < 2; ++mi)
#pragma unroll
      for (int r = 0; r < 4; ++r) part[mi][r] += __shfl_xor(part[mi][r], off);
  if (l16 == 0) {
#pragma unroll
    for (int mi = 0; mi < 2; ++mi)
#pragma unroll
      for (int r = 0; r < 4; ++r)
        red[wn][wm * 32 + mi * 16 + khi * 4 + r] = part[mi][r];
  }
  __syncthreads();
#pragma unroll
  for (int mi = 0; mi < 2; ++mi)
#pragma unroll
    for (int r = 0; r < 4; ++r) {
      int row = wm * 32 + mi * 16 + khi * 4 + r;
      float ss = red[0][row] + red[1][row] + red[2][row] + red[3][row];
      float scale = 1.f / fmaxf(sqrtf(ss), 1e-12f);
#pragma unroll
      for (int ni = 0; ni < 4; ++ni) {
        int col = wn * 64 + ni * 16 + l16;
        float val = acc[mi][ni][r] * scale;
        if (isK) {
          Km[(long)(r0 + row) * 256 + col] = val;
          Kmb[(long)(r0 + row) * 256 + col] = f2bf(val);
        } else {
          Qm[(long)(r0 + row) * 256 + col] = f2bf(val);
        }
      }
    }
}

// ---------------- Kernel 4: beta = sigmoid(x @ beta_w^T) ----------------
__global__ __launch_bounds__(64) void beta_kernel(const float* __restrict__ x,
                                                  const float* __restrict__ bw,
                                                  float* __restrict__ beta) {
  long row = blockIdx.x;
  int lane = threadIdx.x;
  const float* xr = x + row * 512;
  float xv[8];
#pragma unroll
  for (int j = 0; j < 8; ++j) xv[j] = xr[lane + j * 64];
#pragma unroll
  for (int hh = 0; hh < 8; ++hh) {
    const float* wr = bw + hh * 512;
    float p = 0.f;
#pragma unroll
    for (int j = 0; j < 8; ++j) p += xv[j] * wr[lane + j * 64];
#pragma unroll
    for (int off = 32; off > 0; off >>= 1) p += __shfl_down(p, off);
    if (lane == 0) beta[row * 8 + hh] = 1.f / (1.f + expf(-p));
  }
}

// ---------------- Kernel 5a: per-chunk W = (I + diag(b) L)^-1 diag(b) ---
// In-register triangular solve (x[64], fully unrolled); W written directly.
__global__ __launch_bounds__(256) void wprep_kernel(
    const float* __restrict__ Km, const float* __restrict__ beta,
    unsigned short* __restrict__ Whi, unsigned short* __restrict__ Wlo) {
  __shared__ unsigned short Khi[64 * 256];
  __shared__ unsigned short Klo[64 * 256];
  __shared__ float Bm[64 * 64];
  __shared__ float bv[64];
  int blk = blockIdx.x, ch = blk & 31, bh = blk >> 5;
  int b = bh >> 3, h = bh & 7;
  int t0 = ch * 64;
  int tid = threadIdx.x, wave = tid >> 6, lane = tid & 63;
  int khi = lane >> 4, l16 = lane & 15;
  {
    int t = tid >> 2, n0 = (tid & 3) * 64;
    const float* kp = Km + ((long)(b * TSEQ) + t0 + t) * 256 + n0;
    char* ph = (char*)Khi + t * 512;
    char* pl = (char*)Klo + t * 512;
#pragma unroll
    for (int i = 0; i < 64; i += 8) {
      float4 v0 = *(const float4*)(kp + i);
      float4 v1 = *(const float4*)(kp + i + 4);
      float vv[8] = {v0.x, v0.y, v0.z, v0.w, v1.x, v1.y, v1.z, v1.w};
      unsigned int hw[4], lw[4];
#pragma unroll
      for (int q = 0; q < 4; ++q) {
        unsigned short h0 = f2bf(vv[2 * q]), h1 = f2bf(vv[2 * q + 1]);
        hw[q] = (unsigned)h0 | ((unsigned)h1 << 16);
        lw[q] = (unsigned)f2bf(vv[2 * q] - bf2f(h0)) |
                ((unsigned)f2bf(vv[2 * q + 1] - bf2f(h1)) << 16);
      }
      int off = ((n0 + i) * 2) ^ ((t & 7) << 4);
      *(uint4*)(ph + off) = make_uint4(hw[0], hw[1], hw[2], hw[3]);
      *(uint4*)(pl + off) = make_uint4(lw[0], lw[1], lw[2], lw[3]);
    }
  }
  if (tid < 64) bv[tid] = beta[((long)(b * TSEQ) + t0 + tid) * 8 + h];
  __syncthreads();
  f32x4 sacc[4] = {};
#pragma unroll
  for (int ks = 0; ks < 8; ++ks) {
    int arow = wave * 16 + l16;
    int koff = (ks * 32 + khi * 8) * 2;
    bf16x8 ah = *(const bf16x8*)((const char*)Khi + arow * 512 + (koff ^ ((arow & 7) << 4)));
    bf16x8 al = *(const bf16x8*)((const char*)Klo + arow * 512 + (koff ^ ((arow & 7) << 4)));
    bf16x8 bhf[4], blf[4];
#pragma unroll
    for (int si = 0; si < 4; ++si) {
      int brow = si * 16 + l16;
      bhf[si] = *(const bf16x8*)((const char*)Khi + brow * 512 + (koff ^ ((brow & 7) << 4)));
      blf[si] = *(const bf16x8*)((const char*)Klo + brow * 512 + (koff ^ ((brow & 7) << 4)));
    }
#pragma unroll
    for (int si = 0; si < 4; ++si) sacc[si] = mfma16(ah, bhf[si], sacc[si]);
#pragma unroll
    for (int si = 0; si < 4; ++si) sacc[si] = mfma16(ah, blf[si], sacc[si]);
#pragma unroll
    for (int si = 0; si < 4; ++si) sacc[si] = mfma16(al, bhf[si], sacc[si]);
  }
#pragma unroll
  for (int si = 0; si < 4; ++si)
#pragma unroll
    for (int r = 0; r < 4; ++r) {
      int t = wave * 16 + khi * 4 + r, s = si * 16 + l16;
      Bm[t * 64 + s] = (s < t) ? bv[t] * sacc[si][r] : 0.f;
    }
  __syncthreads();
  if (wave == 0) {
    // forward substitution, columns on lanes, X rows in registers.
    // Bm rows are zero-padded at r>=t, so full-width dots are exact.
    float x[64];
#pragma unroll
    for (int i = 0; i < 64; ++i) x[i] = 0.f;
    long base = (long)blk * 4096;
    const f32x4* BmV = (const f32x4*)Bm;
    float bl = bv[lane];
#pragma unroll
    for (int t = 0; t < 64; ++t) {
      float p0 = 0.f, p1 = 0.f, p2 = 0.f, p3 = 0.f;
#pragma unroll
      for (int rq = 0; rq < 16; ++rq) {
        f32x4 b4 = BmV[t * 16 + rq];
        p0 = fmaf(b4.x, x[rq * 4 + 0], p0);
        p1 = fmaf(b4.y, x[rq * 4 + 1], p1);
        p2 = fmaf(b4.z, x[rq * 4 + 2], p2);
        p3 = fmaf(b4.w, x[rq * 4 + 3], p3);
      }
      float xv = ((lane == t) ? 1.f : 0.f) - ((p0 + p1) + (p2 + p3));
      x[t] = xv;
      float wv = xv * bl;
      unsigned short hi = f2bf(wv);
      Whi[base + t * 64 + lane] = hi;
      Wlo[base + t * 64 + lane] = f2bf(wv - bf2f(hi));
    }
  }
}

// ---------------- Kernel 5b: chunked scan, M in MFMA accumulators -------
// All staging via global_load_lds (inverse-swizzled source). Kr prefetched
// one chunk ahead; Krt (K^T tile) overlays the dead W buffer.
__global__ __launch_bounds__(256) void cscan_kernel(
    const unsigned short* __restrict__ Kb,    // [B][2048][256] bf16
    const unsigned short* __restrict__ KbT,   // [B][256][2048] bf16
    const float* __restrict__ xn,
    const float* __restrict__ M0,
    const unsigned short* __restrict__ Whi,
    const unsigned short* __restrict__ Wlo,
    float* __restrict__ Mout) {
  __shared__ unsigned short Mthi[64 * 256];   // [d][n] swz ((d&7)<<4)
  __shared__ unsigned short Mtlo[64 * 256];
  __shared__ unsigned short Kr[64 * 256];     // [t][n] swz KSW(t)
  __shared__ unsigned short Pool[16384];      // Wh | Wl  (overlaid by Krt [n][t])
  __shared__ unsigned short RU0[64 * 64];     // [d][t] swz ((d&7)<<4)
  __shared__ unsigned short RU1[64 * 64];
  unsigned short* Wh = Pool;
  unsigned short* Wl = Pool + 4096;
  unsigned short* Krt = Pool;
  int bh = blockIdx.x, dsl = blockIdx.y;
  int b = bh >> 3;
  int d0 = dsl * 64;
  int tid = threadIdx.x, wave = tid >> 6, lane = tid & 63;
  int khi = lane >> 4, l16 = lane & 15;
  const char* KbBase = (const char*)(Kb + (long)b * TSEQ * 256);

  f32x4 macc[4][4];
  const float* M0p = M0 + (long)bh * 256 * 512;
#pragma unroll
  for (int ni = 0; ni < 4; ++ni)
#pragma unroll
    for (int di = 0; di < 4; ++di)
#pragma unroll
      for (int r = 0; r < 4; ++r) {
        int n = wave * 64 + ni * 16 + khi * 4 + r;
        macc[ni][di][r] = M0p[(long)n * 512 + d0 + di * 16 + l16];
      }
#pragma unroll
  for (int ni = 0; ni < 4; ++ni)
#pragma unroll
    for (int di = 0; di < 4; ++di) {
      int n = wave * 64 + ni * 16 + khi * 4;
      int d = di * 16 + l16;
      unsigned short hq[4], lq[4];
#pragma unroll
      for (int r = 0; r < 4; ++r) {
        float v = macc[ni][di][r];
        hq[r] = f2bf(v); lq[r] = f2bf(v - bf2f(hq[r]));
      }
      int off = d * 512 + (((n * 2) ^ ((d & 7) << 4)));
      *(uint2*)((char*)Mthi + off) =
          make_uint2((unsigned)hq[0] | ((unsigned)hq[1] << 16),
                     (unsigned)hq[2] | ((unsigned)hq[3] << 16));
      *(uint2*)((char*)Mtlo + off) =
          make_uint2((unsigned)lq[0] | ((unsigned)lq[1] << 16),
                     (unsigned)lq[2] | ((unsigned)lq[3] << 16));
    }
  // prologue: stage Kr(ch=0)
#pragma unroll
  for (int q = 0; q < 8; ++q) {
    int lin = tid * 16 + q * 4096;
    int t = lin >> 9;
    int c = (lin & 511) ^ KSW(t);
    __builtin_amdgcn_global_load_lds((const g_uint*)(KbBase + (long)t * 512 + c),
                                     (lds_uint*)((char*)Kr + lin), 16, 0, 0);
  }
  __syncthreads();

  for (int ch = 0; ch < 32; ++ch) {
    int tc0 = ch * 64;
    // stage W(ch) into Pool
    {
      const char* whb = (const char*)(Whi + ((long)bh * 32 + ch) * 4096);
      const char* wlb = (const char*)(Wlo + ((long)bh * 32 + ch) * 4096);
#pragma unroll
      for (int q = 0; q < 2; ++q) {
        int lin = tid * 16 + q * 4096;
        int t = lin >> 7, c = lin & 127;
        int sb = t * 128 + (c ^ ((t & 7) << 4));
        __builtin_amdgcn_global_load_lds((const g_uint*)(whb + sb),
                                         (lds_uint*)((char*)Wh + lin), 16, 0, 0);
        __builtin_amdgcn_global_load_lds((const g_uint*)(wlb + sb),
                                         (lds_uint*)((char*)Wl + lin), 16, 0, 0);
      }
    }
    // V -> regs
    float vreg[4][4];
    {
      const float* vp = xn + ((long)b * TSEQ + tc0) * 512 + d0;
#pragma unroll
      for (int di = 0; di < 4; ++di)
#pragma unroll
        for (int r = 0; r < 4; ++r) {
          int t = wave * 16 + khi * 4 + r;
          vreg[di][r] = vp[(long)t * 512 + di * 16 + l16];
        }
    }
    __syncthreads();  // B1: Kr(ch), W(ch) landed

    // A = Kr * (Mthi + Mtlo)
    f32x4 aacc[4] = {};
#pragma unroll
    for (int ks = 0; ks < 8; ++ks) {
      int arow = wave * 16 + l16;
      int koff = (ks * 32 + khi * 8) * 2;
      bf16x8 af = *(const bf16x8*)((const char*)Kr + arow * 512 + (koff ^ KSW(arow)));
      bf16x8 mh[4], ml[4];
#pragma unroll
      for (int di = 0; di < 4; ++di) {
        int drow = di * 16 + l16;
        mh[di] = *(const bf16x8*)((const char*)Mthi + drow * 512 + (koff ^ ((drow & 7) << 4)));
        ml[di] = *(const bf16x8*)((const char*)Mtlo + drow * 512 + (koff ^ ((drow & 7) << 4)));
      }
#pragma unroll
      for (int di = 0; di < 4; ++di) aacc[di] = mfma16(af, mh[di], aacc[di]);
#pragma unroll
      for (int di = 0; di < 4; ++di) aacc[di] = mfma16(af, ml[di], aacc[di]);
    }
    // R = V - A -> RU0
#pragma unroll
    for (int di = 0; di < 4; ++di) {
      int t = wave * 16 + khi * 4;
      int d = di * 16 + l16;
      unsigned short rq[4];
#pragma unroll
      for (int r = 0; r < 4; ++r) rq[r] = f2bf(vreg[di][r] - aacc[di][r]);
      int off = d * 128 + (((t * 2) ^ ((d & 7) << 4)));
      *(uint2*)((char*)RU0 + off) =
          make_uint2((unsigned)rq[0] | ((unsigned)rq[1] << 16),
                     (unsigned)rq[2] | ((unsigned)rq[3] << 16));
    }
    __syncthreads();  // B2: R visible; Kr reads done

    // prefetch Kr(ch+1)
    if (ch + 1 < 32) {
      const char* kb2 = KbBase + (long)(tc0 + 64) * 512;
#pragma unroll
      for (int q = 0; q < 8; ++q) {
        int lin = tid * 16 + q * 4096;
        int t = lin >> 9;
        int c = (lin & 511) ^ KSW(t);
        __builtin_amdgcn_global_load_lds((const g_uint*)(kb2 + (long)t * 512 + c),
                                         (lds_uint*)((char*)Kr + lin), 16, 0, 0);
      }
    }

    // U = (Wh + Wl) * R
    f32x4 uacc[4] = {};
#pragma unroll
    for (int ks = 0; ks < 2; ++ks) {
      int arow = wave * 16 + l16;
      int soff = (ks * 32 + khi * 8) * 2;
      bf16x8 wh_ = *(const bf16x8*)((const char*)Wh + arow * 128 + (soff ^ ((arow & 7) << 4)));
      bf16x8 wl_ = *(const bf16x8*)((const char*)Wl + arow * 128 + (soff ^ ((arow & 7) << 4)));
      bf16x8 rf[4];
#pragma unroll
      for (int di = 0; di < 4; ++di) {
        int drow = di * 16 + l16;
        rf[di] = *(const bf16x8*)((const char*)RU0 + drow * 128 + (soff ^ ((drow & 7) << 4)));
      }
#pragma unroll
      for (int di = 0; di < 4; ++di) uacc[di] = mfma16(wh_, rf[di], uacc[di]);
#pragma unroll
      for (int di = 0; di < 4; ++di) uacc[di] = mfma16(wl_, rf[di], uacc[di]);
    }
    __syncthreads();  // B3: W reads done -> Pool free

    // prefetch Krt(ch) into Pool (overlays Wh/Wl)
    {
#pragma unroll
      for (int q = 0; q < 8; ++q) {
        int lin = tid * 16 + q * 4096;
        int n = lin >> 7, c = lin & 127;
        long sb = ((long)(b * 256 + n)) * 4096 + (long)tc0 * 2 + (c ^ ((n & 7) << 4));
        __builtin_amdgcn_global_load_lds((const g_uint*)((const char*)KbT + sb),
                                         (lds_uint*)((char*)Krt + lin), 16, 0, 0);
      }
    }
    // write U hi/lo
#pragma unroll
    for (int di = 0; di < 4; ++di) {
      int t = wave * 16 + khi * 4;
      int d = di * 16 + l16;
      unsigned short hq[4], lq[4];
#pragma unroll
      for (int r = 0; r < 4; ++r) {
        float u = uacc[di][r];
        hq[r] = f2bf(u); lq[r] = f2bf(u - bf2f(hq[r]));
      }
      int off = d * 128 + (((t * 2) ^ ((d & 7) << 4)));
      *(uint2*)((char*)RU0 + off) =
          make_uint2((unsigned)hq[0] | ((unsigned)hq[1] << 16),
                     (unsigned)hq[2] | ((unsigned)hq[3] << 16));
      *(uint2*)((char*)RU1 + off) =
          make_uint2((unsigned)lq[0] | ((unsigned)lq[1] << 16),
                     (unsigned)lq[2] | ((unsigned)lq[3] << 16));
    }
    __syncthreads();  // B4: Krt landed, U visible

    // M += Krt^T-read * (Uhi + Ulo)
#pragma unroll
    for (int ks = 0; ks < 2; ++ks) {
      int toff = (ks * 32 + khi * 8) * 2;
      bf16x8 ka[4];
#pragma unroll
      for (int ni = 0; ni < 4; ++ni) {
        int n = wave * 64 + ni * 16 + l16;
        ka[ni] = *(const bf16x8*)((const char*)Krt + n * 128 + (toff ^ ((n & 7) << 4)));
      }
      bf16x8 uh[4], ul[4];
#pragma unroll
      for (int di = 0; di < 4; ++di) {
        int drow = di * 16 + l16;
        uh[di] = *(const bf16x8*)((const char*)RU0 + drow * 128 + (toff ^ ((drow & 7) << 4)));
        ul[di] = *(const bf16x8*)((const char*)RU1 + drow * 128 + (toff ^ ((drow & 7) << 4)));
      }
#pragma unroll
      for (int ni = 0; ni < 4; ++ni)
#pragma unroll
        for (int di = 0; di < 4; ++di)
          macc[ni][di] = mfma16(ka[ni], uh[di], macc[ni][di]);
#pragma unroll
      for (int ni = 0; ni < 4; ++ni)
#pragma unroll
        for (int di = 0; di < 4; ++di)
          macc[ni][di] = mfma16(ka[ni], ul[di], macc[ni][di]);
    }
    // Mt rewrite (no barrier needed before: disjoint buffers)
#pragma unroll
    for (int ni = 0; ni < 4; ++ni)
#pragma unroll
      for (int di = 0; di < 4; ++di) {
        int n = wave * 64 + ni * 16 + khi * 4;
        int d = di * 16 + l16;
        unsigned short hq[4], lq[4];
#pragma unroll
        for (int r = 0; r < 4; ++r) {
          float v = macc[ni][di][r];
          hq[r] = f2bf(v); lq[r] = f2bf(v - bf2f(hq[r]));
        }
        int off = d * 512 + (((n * 2) ^ ((d & 7) << 4)));
        *(uint2*)((char*)Mthi + off) =
            make_uint2((unsigned)hq[0] | ((unsigned)hq[1] << 16),
                       (unsigned)hq[2] | ((unsigned)hq[3] << 16));
        *(uint2*)((char*)Mtlo + off) =
            make_uint2((unsigned)lq[0] | ((unsigned)lq[1] << 16),
                       (unsigned)lq[2] | ((unsigned)lq[3] << 16));
      }
    __syncthreads();  // B6: Mt ready for next chunk
  }

  float* Mo = Mout + (long)bh * 256 * 512;
#pragma unroll
  for (int ni = 0; ni < 4; ++ni)
#pragma unroll
    for (int di = 0; di < 4; ++di)
#pragma unroll
      for (int r = 0; r < 4; ++r) {
        int n = wave * 64 + ni * 16 + khi * 4 + r;
        Mo[(long)n * 512 + d0 + di * 16 + l16] = macc[ni][di][r];
      }
}

// ---------------- Kernel 6: causal attention y_standard (v3) ------------
// dch merged: block = 128 t-rows x full 512 d-cols; S computed once.
// grid (32 bh, 8 bp): same-bh blocks land on the same XCD for L2 sharing.
__global__ __launch_bounds__(512) void attn_kernel(
    const unsigned short* __restrict__ QR,
    const unsigned short* __restrict__ Vt,
    float* __restrict__ Y) {
  int bh = blockIdx.x;     // 0..31
  int bp = blockIdx.y;     // 0..7
  int wave = threadIdx.x >> 6, lane = threadIdx.x & 63;
  int wr = wave >> 2, wc = wave & 3;
  int khi = lane >> 4, l16 = lane & 15;
  __shared__ unsigned short K_lds[64 * 256];
  __shared__ unsigned short S_lds[128 * 64];
  const unsigned short* QRb = QR + (long)bh * TSEQ * 256;
  const unsigned short* Vtb = Vt + (long)bh * 512 * TSEQ;
  float* yb = Y + (long)bh * TSEQ * 512;
  int lin_base = wave * 4096 + lane * 16;

#pragma unroll 1
  for (int half = 0; half < 2; ++half) {
    int bt = half ? bp : (15 - bp);
    int t0 = bt * 128;
    int nst = 2 * bt + 2;

    bf16x8 qa[8];
    {
      int trow = t0 + wave * 16 + l16;
      const unsigned short* qp = QRb + (long)trow * 256 + khi * 8;
#pragma unroll
      for (int ks = 0; ks < 8; ++ks) qa[ks] = *(const bf16x8*)(qp + ks * 32);
    }
    f32x4 acc[4][8] = {};

    // prologue: stage K tile st=0
#pragma unroll
    for (int q = 0; q < 4; ++q) {
      int linear = lin_base + q * 1024;
      int row = linear >> 9;
      int nc2 = (linear & 511) ^ ((row & 7) << 4);
      __builtin_amdgcn_global_load_lds(
          (const g_uint*)((const char*)QRb + (long)row * 512 + nc2),
          (lds_uint*)((char*)K_lds + (wave * 4 + q) * 1024), 16, 0, 0);
    }
    __syncthreads();

    for (int st = 0; st < nst; ++st) {
      int s0 = st * 64;
      // phase 1: S = Q K^T
      f32x4 sacc[4] = {};
#pragma unroll
      for (int ks = 0; ks < 8; ++ks) {
#pragma unroll
        for (int fc = 0; fc < 4; ++fc) {
          int srow = fc * 16 + l16;
          bf16x8 kf = *(const bf16x8*)(
              (const char*)K_lds + srow * 512 + ((ks * 64 + khi * 16) ^ ((srow & 7) << 4)));
          sacc[fc] = mfma16(qa[ks], kf, sacc[fc]);
        }
      }
      // mask (strict lower) + cast + store S
#pragma unroll
      for (int fc = 0; fc < 4; ++fc)
#pragma unroll
        for (int r = 0; r < 4; ++r) {
          int srow = wave * 16 + khi * 4 + r;
          int scol = fc * 16 + l16;
          float v = ((s0 + scol) < (t0 + srow)) ? sacc[fc][r] : 0.f;
          *(unsigned short*)(
              (char*)S_lds + srow * 128 + ((scol * 2) ^ ((srow & 7) << 4))) = f2bf(v);
        }
      __syncthreads();   // S ready, K_lds phase-1 reads done

      // prefetch next K tile (async; drains at loop-end barrier)
      if (st + 1 < nst) {
        long srow_base = (long)(s0 + 64) * 512;
#pragma unroll
        for (int q = 0; q < 4; ++q) {
          int linear = lin_base + q * 1024;
          int row = linear >> 9;
          int nc2 = (linear & 511) ^ ((row & 7) << 4);
          __builtin_amdgcn_global_load_lds(
              (const g_uint*)((const char*)QRb + srow_base + (long)row * 512 + nc2),
              (lds_uint*)((char*)K_lds + (wave * 4 + q) * 1024), 16, 0, 0);
        }
      }
      // phase 2: O += S @ V over full 512 d
#pragma unroll
      for (int k2 = 0; k2 < 2; ++k2) {
        bf16x8 af[4];
#pragma unroll
        for (int mi = 0; mi < 4; ++mi) {
          int row = wr * 64 + mi * 16 + l16;
          af[mi] = *(const bf16x8*)(
              (const char*)S_lds + row * 128 + ((k2 * 64 + khi * 16) ^ ((row & 7) << 4)));
        }
#pragma unroll
        for (int nh = 0; nh < 2; ++nh) {
          bf16x8 bfv[4];
#pragma unroll
          for (int nj = 0; nj < 4; ++nj) {
            int d = wc * 128 + (nh * 4 + nj) * 16 + l16;
            bfv[nj] = *(const bf16x8*)(Vtb + (long)d * TSEQ + s0 + k2 * 32 + khi * 8);
          }
#pragma unroll
          for (int mi = 0; mi < 4; ++mi)
#pragma unroll
            for (int nj = 0; nj < 4; ++nj)
              acc[mi][nh * 4 + nj] = mfma16(af[mi], bfv[nj], acc[mi][nh * 4 + nj]);
        }
      }
      __syncthreads();   // K_lds[st+1] landed, S_lds reads done
    }

#pragma unroll
    for (int mi = 0; mi < 4; ++mi)
#pragma unroll
      for (int ni = 0; ni < 8; ++ni)
#pragma unroll
        for (int r = 0; r < 4; ++r) {
          int trow = t0 + wr * 64 + mi * 16 + khi * 4 + r;
          int d = wc * 128 + ni * 16 + l16;
          yb[(long)trow * 512 + d] = acc[mi][ni][r];
        }
  }
}

// ---------------- Kernel 7: y_memory GEMM + LN + gated combine ----------
__global__ __launch_bounds__(512) void combine_kernel(
    const unsigned short* __restrict__ Qm,
    const unsigned short* __restrict__ M0t,
    const float* __restrict__ mg,
    float* __restrict__ Y) {
  int t0 = blockIdx.x * 64;
  int bh = blockIdx.y;
  int b = bh >> 3, h = bh & 7;
  int wv = threadIdx.x >> 6, lane = threadIdx.x & 63;
  int khi = lane >> 4, l16 = lane & 15;
  __shared__ unsigned short A_lds[64 * 256];
  __shared__ float red_s[8][64], red_q[8][64];
  __shared__ float mu_s[64], inv_s[64];
  {
    const unsigned short* src = Qm + ((long)b * TSEQ + t0) * 256;
#pragma unroll
    for (int p = 0; p < 4; ++p) {
      int row = (threadIdx.x >> 5) + p * 16;
      int nc = (threadIdx.x & 31) * 8;
      bf16x8 v = *reinterpret_cast<const bf16x8*>(src + (long)row * 256 + nc);
      *reinterpret_cast<bf16x8*>((char*)A_lds + row * 512 + ((nc * 2) ^ ((row & 7) << 4))) = v;
    }
  }
  __syncthreads();
  f32x4 acc[4][4] = {};
  const unsigned short* Bp = M0t + (long)bh * 512 * 256;
#pragma unroll
  for (int ks = 0; ks < 8; ++ks) {
    bf16x8 a[4], bfr[4];
#pragma unroll
    for (int mi = 0; mi < 4; ++mi) {
      int row = mi * 16 + l16;
      a[mi] = *reinterpret_cast<const bf16x8*>(
          (const char*)A_lds + row * 512 + ((ks * 64 + khi * 16) ^ ((row & 7) << 4)));
    }
#pragma unroll
    for (int ni = 0; ni < 4; ++ni) {
      int d = wv * 64 + ni * 16 + l16;
      bfr[ni] = *reinterpret_cast<const bf16x8*>(Bp + (long)d * 256 + ks * 32 + khi * 8);
    }
#pragma unroll
    for (int mi = 0; mi < 4; ++mi)
#pragma unroll
      for (int ni = 0; ni < 4; ++ni)
        acc[mi][ni] = mfma16(a[mi], bfr[ni], acc[mi][ni]);
  }
  float ps[4][4], pq[4][4];
#pragma unroll
  for (int mi = 0; mi < 4; ++mi)
#pragma unroll
    for (int r = 0; r < 4; ++r) {
      float s = 0.f, q = 0.f;
#pragma unroll
      for (int ni = 0; ni < 4; ++ni) {
        float v = acc[mi][ni][r];
        s += v; q += v * v;
      }
      ps[mi][r] = s; pq[mi][r] = q;
    }
#pragma unroll
  for (int off = 1; off < 16; off <<= 1)
#pragma unroll
    for (int mi = 0; mi < 4; ++mi)
#pragma unroll
      for (int r = 0; r < 4; ++r) {
        ps[mi][r] += __shfl_xor(ps[mi][r], off);
        pq[mi][r] += __shfl_xor(pq[mi][r], off);
      }
  if (l16 == 0) {
#pragma unroll
    for (int mi = 0; mi < 4; ++mi)
#pragma unroll
      for (int r = 0; r < 4; ++r) {
        int row = mi * 16 + khi * 4 + r;
        red_s[wv][row] = ps[mi][r];
        red_q[wv][row] = pq[mi][r];
      }
  }
  __syncthreads();
  if (threadIdx.x < 64) {
    float s = 0.f, q = 0.f;
#pragma unroll
    for (int w2 = 0; w2 < 8; ++w2) { s += red_s[w2][threadIdx.x]; q += red_q[w2][threadIdx.x]; }
    float mu = s / 512.f;
    float var = q / 512.f - mu * mu;
    mu_s[threadIdx.x] = mu;
    inv_s[threadIdx.x] = rsqrtf(var + 1e-5f);
  }
  __syncthreads();
  float gate = 1.f / (1.f + expf(-mg[h]));
  float omg = 1.f - gate;
  float* yb = Y + ((long)bh * TSEQ + t0) * 512;
#pragma unroll
  for (int mi = 0; mi < 4; ++mi)
#pragma unroll
    for (int r = 0; r < 4; ++r) {
      int row = mi * 16 + khi * 4 + r;
      float mu = mu_s[row], inv = inv_s[row];
#pragma unroll
      for (int ni = 0; ni < 4; ++ni) {
        int d = wv * 64 + ni * 16 + l16;
        long off = (long)row * 512 + d;
        float ymv = (acc[mi][ni][r] - mu) * inv;
        yb[off] = omg * yb[off] + gate * ymv;
      }
    }
}

// ---------------- host launcher -----------------------------------------
extern "C" void kernel_launch(void* const* d_in, const int* in_sizes, int n_in,
                              void* d_out, int out_size, void* d_ws, size_t ws_size,
                              hipStream_t stream) {
  const float* Q      = (const float*)d_in[0];
  const float* V      = (const float*)d_in[1];
  const float* x_raw  = (const float*)d_in[2];
  const float* x_next = (const float*)d_in[3];
  const float* wq     = (const float*)d_in[4];
  const float* wk     = (const float*)d_in[5];
  const float* bw     = (const float*)d_in[6];
  const float* mg     = (const float*)d_in[7];
  const float* M0     = (const float*)d_in[8];
  float* y = (float*)d_out;
  float* Mout = y + (long)32 * 2048 * 512;

  char* ws = (char*)d_ws;
  unsigned short* QR  = (unsigned short*)(ws);                 // 33,554,432 B
  unsigned short* Vt  = (unsigned short*)(ws + 33554432);      // 67,108,864 B
  unsigned short* M0t = (unsigned short*)(ws + 100663296);     //  8,388,608 B
  unsigned short* Qm  = (unsigned short*)(ws + 109051904);     //  4,194,304 B
  float*  Km          = (float*)(ws + 113246208);              //  8,388,608 B
  float*  beta        = (float*)(ws + 121634816);              //    262,144 B
  // Aliased inside the Vt region (all consumed before transposeV writes Vt):
  unsigned short* Whi = (unsigned short*)(ws + 33554432);      //  8,388,608 B
  unsigned short* Wlo = (unsigned short*)(ws + 41943040);      //  8,388,608 B
  unsigned short* Kmb = (unsigned short*)(ws + 50331648);      //  4,194,304 B
  unsigned short* KmT = (unsigned short*)(ws + 54525952);      //  4,194,304 B

  qkm_kernel<<<dim3(128, 2), dim3(512), 0, stream>>>(x_raw, wq, wk, Qm, Km, Kmb);
  transpose_cast_kernel<<<dim3(4, 32, 4), dim3(256), 0, stream>>>(Km, KmT, 2048, 256);
  beta_kernel<<<dim3(8192), dim3(64), 0, stream>>>(x_raw, bw, beta);
  wprep_kernel<<<dim3(1024), dim3(256), 0, stream>>>(Km, beta, Whi, Wlo);
  cscan_kernel<<<dim3(32, 8), dim3(256), 0, stream>>>(Kmb, KmT, x_next, M0, Whi, Wlo, Mout);
  rope_kernel<<<dim3(32768), dim3(256), 0, stream>>>(Q, QR);
  transpose_cast_kernel<<<dim3(8, 32, 32), dim3(256), 0, stream>>>(V, Vt, 2048, 512);
  transpose_cast_kernel<<<dim3(8, 4, 32), dim3(256), 0, stream>>>(M0, M0t, 256, 512);
  attn_kernel<<<dim3(32, 8), dim3(512), 0, stream>>>(QR, Vt, y);
  combine_kernel<<<dim3(32, 32), dim3(512), 0, stream>>>(Qm, M0t, mg, y);
}